// Round 1
// baseline (1796.780 us; speedup 1.0000x reference)
//
#include <hip/hip_runtime.h>
#include <math.h>

#define N_NODES 50000
#define N_EDGES 250000
#define BB      128
#define DD      302
#define QQ      600
#define CC      2000
#define NEG_SLOPE 0.2f

// ---------------------------------------------------------------- CSR build
__global__ void k_deg_init(int* deg, int* cursor) {
    int i = blockIdx.x * blockDim.x + threadIdx.x;
    if (i < N_NODES) { deg[i] = 1; cursor[i] = 0; }  // 1 = self loop
}

__global__ void k_histogram(const int* __restrict__ dst, int* deg) {
    int e = blockIdx.x * blockDim.x + threadIdx.x;
    if (e < N_EDGES) atomicAdd(&deg[dst[e]], 1);
}

__global__ void k_scan_block(const int* __restrict__ deg, int* offs, int* partials) {
    __shared__ int sh[256];
    int i = blockIdx.x * 256 + threadIdx.x;
    int v = (i < N_NODES) ? deg[i] : 0;
    sh[threadIdx.x] = v;
    __syncthreads();
    for (int d = 1; d < 256; d <<= 1) {
        int t = (threadIdx.x >= d) ? sh[threadIdx.x - d] : 0;
        __syncthreads();
        sh[threadIdx.x] += t;
        __syncthreads();
    }
    if (i < N_NODES) offs[i] = sh[threadIdx.x] - v;   // exclusive
    if (threadIdx.x == 255) partials[blockIdx.x] = sh[255];
}

__global__ void k_scan_partials(int* partials, int nb) {
    __shared__ int sh[256];
    int v = (threadIdx.x < nb) ? partials[threadIdx.x] : 0;
    sh[threadIdx.x] = v;
    __syncthreads();
    for (int d = 1; d < 256; d <<= 1) {
        int t = (threadIdx.x >= d) ? sh[threadIdx.x - d] : 0;
        __syncthreads();
        sh[threadIdx.x] += t;
        __syncthreads();
    }
    if (threadIdx.x < nb) partials[threadIdx.x] = sh[threadIdx.x] - v;  // exclusive
}

__global__ void k_scan_add(int* offs, const int* __restrict__ partials) {
    int i = blockIdx.x * 256 + threadIdx.x;
    if (i < N_NODES) offs[i] += partials[blockIdx.x];
}

__global__ void k_scatter(const int* __restrict__ src, const int* __restrict__ dst,
                          const int* __restrict__ offs, int* cursor, int* esrc) {
    int i = blockIdx.x * blockDim.x + threadIdx.x;
    if (i < N_EDGES) {
        int d = dst[i];
        int pos = offs[d] + atomicAdd(&cursor[d], 1);
        esrc[pos] = src[i];
    } else if (i < N_EDGES + N_NODES) {
        int n = i - N_EDGES;
        int pos = offs[n] + atomicAdd(&cursor[n], 1);
        esrc[pos] = n;   // self loop
    }
}

// ---------------------------------------------------------------- SGEMM  C = A @ B^T
// A: [M, DD], B: [DD, DD] row-major, C[m,n] = sum_k A[m,k]*B[n,k]
#define BM 64
#define BN 64
#define BK 16
__global__ __launch_bounds__(256) void k_gemm(const float* __restrict__ A,
                                              const float* __restrict__ B,
                                              float* __restrict__ C, int M) {
    __shared__ float As[BK][BM + 4];   // +4 pad: 16B-aligned b128 reads, conflict-light writes
    __shared__ float Bs[BK][BN + 4];
    int m0 = blockIdx.y * BM;
    int n0 = blockIdx.x * BN;
    int tid = threadIdx.x;
    int tr = tid >> 4;    // 0..15
    int tc = tid & 15;    // 0..15
    float acc[4][4] = {};
    for (int k0 = 0; k0 < DD; k0 += BK) {
        #pragma unroll
        for (int j = 0; j < 4; j++) {
            int e = tid + 256 * j;     // 0..1023
            int r = e >> 4;            // 0..63
            int k = e & 15;
            int gk = k0 + k;
            int gm = m0 + r;
            float va = 0.f;
            if (gm < M && gk < DD) va = A[(size_t)gm * DD + gk];
            As[k][r] = va;
            int gn = n0 + r;
            float vb = 0.f;
            if (gn < DD && gk < DD) vb = B[(size_t)gn * DD + gk];
            Bs[k][r] = vb;
        }
        __syncthreads();
        #pragma unroll
        for (int k = 0; k < BK; k++) {
            float a[4], b[4];
            #pragma unroll
            for (int i = 0; i < 4; i++) a[i] = As[k][tr * 4 + i];
            #pragma unroll
            for (int j = 0; j < 4; j++) b[j] = Bs[k][tc * 4 + j];
            #pragma unroll
            for (int i = 0; i < 4; i++)
                #pragma unroll
                for (int j = 0; j < 4; j++)
                    acc[i][j] += a[i] * b[j];
        }
        __syncthreads();
    }
    #pragma unroll
    for (int i = 0; i < 4; i++) {
        int gm = m0 + tr * 4 + i;
        if (gm >= M) continue;
        #pragma unroll
        for (int j = 0; j < 4; j++) {
            int gn = n0 + tc * 4 + j;
            if (gn < DD) C[(size_t)gm * DD + gn] = acc[i][j];
        }
    }
}

// ---------------------------------------------------------------- per-node attention dots
__global__ void k_attdots(const float* __restrict__ h, const float* __restrict__ att_src,
                          const float* __restrict__ att_dst, float* a_s, float* a_d) {
    int gid = blockIdx.x * blockDim.x + threadIdx.x;
    int n = gid >> 6, lane = gid & 63;
    if (n >= N_NODES) return;
    const float* row = h + (size_t)n * DD;
    float ss = 0.f, sd = 0.f;
    for (int j = lane; j < DD; j += 64) {
        float v = row[j];
        ss += v * att_src[j];
        sd += v * att_dst[j];
    }
    for (int off = 32; off; off >>= 1) {
        ss += __shfl_down(ss, off);
        sd += __shfl_down(sd, off);
    }
    if (lane == 0) { a_s[n] = ss; a_d[n] = sd; }
}

// ---------------------------------------------------------------- softmax-aggregate (wave / dst node)
__global__ __launch_bounds__(256) void k_aggregate(const float* __restrict__ h,
                                                   const float* __restrict__ a_s,
                                                   const float* __restrict__ a_d,
                                                   const int* __restrict__ offs,
                                                   const int* __restrict__ deg,
                                                   const int* __restrict__ esrc,
                                                   const float* __restrict__ bias,
                                                   float* __restrict__ out) {
    int gid = blockIdx.x * blockDim.x + threadIdx.x;
    int n = gid >> 6, lane = gid & 63;
    if (n >= N_NODES) return;
    int beg = offs[n], cnt = deg[n];
    float adn = a_d[n];
    // pass 1: max
    float m = -INFINITY;
    for (int i = lane; i < cnt; i += 64) {
        float e = a_s[esrc[beg + i]] + adn;
        e = (e > 0.f) ? e : NEG_SLOPE * e;
        m = fmaxf(m, e);
    }
    for (int off = 32; off; off >>= 1) m = fmaxf(m, __shfl_xor(m, off));
    // pass 2: sum of exp
    float den = 0.f;
    for (int i = lane; i < cnt; i += 64) {
        float e = a_s[esrc[beg + i]] + adn;
        e = (e > 0.f) ? e : NEG_SLOPE * e;
        den += __expf(e - m);
    }
    for (int off = 32; off; off >>= 1) den += __shfl_xor(den, off);
    float inv_den = 1.f / den;
    // pass 3: weighted feature accumulate
    float acc[5] = {0.f, 0.f, 0.f, 0.f, 0.f};
    for (int i = 0; i < cnt; i++) {
        int s = esrc[beg + i];
        float e = a_s[s] + adn;
        e = (e > 0.f) ? e : NEG_SLOPE * e;
        float w = __expf(e - m) * inv_den;
        const float* row = h + (size_t)s * DD;
        #pragma unroll
        for (int j = 0; j < 5; j++) {
            int f = lane + 64 * j;
            if (f < DD) acc[j] += w * row[f];
        }
    }
    #pragma unroll
    for (int j = 0; j < 5; j++) {
        int f = lane + 64 * j;
        if (f < DD) {
            float v = acc[j] + bias[f];
            out[(size_t)n * DD + f] = fmaxf(v, 0.f);   // all 3 layers have trailing relu
        }
    }
}

// ---------------------------------------------------------------- pooling pieces
__global__ void k_qp(const float* __restrict__ query, const float* __restrict__ attW,
                     float* qp) {
    int b = blockIdx.x;
    int d = threadIdx.x;
    if (d >= DD) return;
    float acc = 0.f;
    for (int q = 0; q < QQ; q++) acc += query[(size_t)b * QQ + q] * attW[(size_t)q * DD + d];
    qp[(size_t)b * DD + d] = acc;
}

__global__ void k_gzero(int* gcnt) {
    if (threadIdx.x < BB) gcnt[threadIdx.x] = 0;
}

__global__ void k_gcount(const int* __restrict__ batch, int* gcnt) {
    int i = blockIdx.x * blockDim.x + threadIdx.x;
    if (i < N_NODES) atomicAdd(&gcnt[batch[i]], 1);
}

__global__ void k_gscan(const int* __restrict__ gcnt, int* goffs) {
    __shared__ int sh[BB];
    int t = threadIdx.x;
    if (t < BB) sh[t] = gcnt[t];
    __syncthreads();
    if (t == 0) {
        int run = 0;
        for (int i = 0; i < BB; i++) { int v = sh[i]; sh[i] = run; run += v; }
    }
    __syncthreads();
    if (t < BB) goffs[t] = sh[t];
}

__global__ void k_scores(const float* __restrict__ h, const float* __restrict__ qp,
                         const int* __restrict__ batch, float* sarr) {
    int gid = blockIdx.x * blockDim.x + threadIdx.x;
    int n = gid >> 6, lane = gid & 63;
    if (n >= N_NODES) return;
    const float* row = h + (size_t)n * DD;
    const float* q = qp + (size_t)batch[n] * DD;
    float acc = 0.f;
    for (int j = lane; j < DD; j += 64) acc += row[j] * q[j];
    for (int off = 32; off; off >>= 1) acc += __shfl_down(acc, off);
    if (lane == 0) sarr[n] = acc * 0.04082482904638630f;   // 1/sqrt(600)
}

__global__ __launch_bounds__(256) void k_pool(const float* __restrict__ h,
                                              const float* __restrict__ sarr,
                                              const int* __restrict__ goffs,
                                              const int* __restrict__ gcnt,
                                              float* __restrict__ pooledrelu) {
    int b = blockIdx.x;
    int beg = goffs[b], cnt = gcnt[b];
    __shared__ float red[256];
    // max
    float m = -INFINITY;
    for (int i = threadIdx.x; i < cnt; i += 256) m = fmaxf(m, sarr[beg + i]);
    red[threadIdx.x] = m;
    __syncthreads();
    for (int d = 128; d; d >>= 1) {
        if (threadIdx.x < d) red[threadIdx.x] = fmaxf(red[threadIdx.x], red[threadIdx.x + d]);
        __syncthreads();
    }
    m = red[0];
    __syncthreads();
    // sum exp
    float den = 0.f;
    for (int i = threadIdx.x; i < cnt; i += 256) den += __expf(sarr[beg + i] - m);
    red[threadIdx.x] = den;
    __syncthreads();
    for (int d = 128; d; d >>= 1) {
        if (threadIdx.x < d) red[threadIdx.x] += red[threadIdx.x + d];
        __syncthreads();
    }
    den = red[0];
    float inv = (cnt > 0) ? 1.f / den : 0.f;
    // weighted accumulate
    float acc0 = 0.f, acc1 = 0.f;
    int f0 = threadIdx.x, f1 = threadIdx.x + 256;
    for (int i = 0; i < cnt; i++) {
        float w = __expf(sarr[beg + i] - m) * inv;
        const float* row = h + (size_t)(beg + i) * DD;
        if (f0 < DD) acc0 += w * row[f0];
        if (f1 < DD) acc1 += w * row[f1];
    }
    if (f0 < DD) pooledrelu[(size_t)b * DD + f0] = fmaxf(acc0, 0.f);
    if (f1 < DD) pooledrelu[(size_t)b * DD + f1] = fmaxf(acc1, 0.f);
}

__global__ __launch_bounds__(256) void k_linear(const float* __restrict__ pr,
                                                const float* __restrict__ lin_w,
                                                const float* __restrict__ lin_b,
                                                float* __restrict__ out) {
    int b = blockIdx.x;
    __shared__ float p[DD];
    for (int i = threadIdx.x; i < DD; i += 256) p[i] = pr[(size_t)b * DD + i];
    __syncthreads();
    for (int c = threadIdx.x; c < CC; c += 256) {
        const float* wrow = lin_w + (size_t)c * DD;
        float acc = lin_b[c];
        for (int d = 0; d < DD; d++) acc += p[d] * wrow[d];
        out[(size_t)b * CC + c] = acc;
    }
}

// ---------------------------------------------------------------- launch
extern "C" void kernel_launch(void* const* d_in, const int* in_sizes, int n_in,
                              void* d_out, int out_size, void* d_ws, size_t ws_size,
                              hipStream_t stream) {
    const float* x        = (const float*)d_in[0];
    const int*   edges    = (const int*)d_in[1];   // [2, E]
    const float* query    = (const float*)d_in[2];
    const int*   batch    = (const int*)d_in[3];
    const float* theta    = (const float*)d_in[4];
    const float* att_src  = (const float*)d_in[5];
    const float* att_dst  = (const float*)d_in[6];
    const float* gat_bias = (const float*)d_in[7];
    const float* attW     = (const float*)d_in[8];
    const float* lin_w    = (const float*)d_in[9];
    const float* lin_b    = (const float*)d_in[10];
    float* out = (float*)d_out;

    char* ws = (char*)d_ws;
    size_t off = 0;
    auto alloc = [&](size_t bytes) -> void* {
        off = (off + 255) & ~(size_t)255;
        void* p = ws + off;
        off += bytes;
        return p;
    };

    float* G    = (float*)alloc((size_t)N_NODES * DD * 4);   // gemm output
    float* P    = (float*)alloc((size_t)N_NODES * DD * 4);   // layer output
    float* a_s  = (float*)alloc((size_t)N_NODES * 4);
    float* a_d  = (float*)alloc((size_t)N_NODES * 4);
    float* sarr = (float*)alloc((size_t)N_NODES * 4);
    int* deg    = (int*)alloc((size_t)N_NODES * 4);
    int* cursor = (int*)alloc((size_t)N_NODES * 4);
    int* offs   = (int*)alloc((size_t)N_NODES * 4);
    int* esrc   = (int*)alloc((size_t)(N_EDGES + N_NODES) * 4);
    int* partials = (int*)alloc(256 * 4);
    int* gcnt   = (int*)alloc(BB * 4);
    int* goffs  = (int*)alloc(BB * 4);
    float* qp   = (float*)alloc((size_t)BB * DD * 4);
    float* pr   = (float*)alloc((size_t)BB * DD * 4);

    const int* e_src = edges;
    const int* e_dst = edges + N_EDGES;

    const int NB_SCAN = (N_NODES + 255) / 256;   // 196

    // ---- CSR build (once; edges fixed within a call)
    k_deg_init<<<NB_SCAN, 256, 0, stream>>>(deg, cursor);
    k_histogram<<<(N_EDGES + 255) / 256, 256, 0, stream>>>(e_dst, deg);
    k_scan_block<<<NB_SCAN, 256, 0, stream>>>(deg, offs, partials);
    k_scan_partials<<<1, 256, 0, stream>>>(partials, NB_SCAN);
    k_scan_add<<<NB_SCAN, 256, 0, stream>>>(offs, partials);
    k_scatter<<<(N_EDGES + N_NODES + 255) / 256, 256, 0, stream>>>(e_src, e_dst, offs, cursor, esrc);

    // ---- 3 GAT layers
    dim3 gemm_grid((DD + BN - 1) / BN, (N_NODES + BM - 1) / BM);
    int wave_blocks = (N_NODES + 3) / 4;    // 4 waves / 256-thread block
    const float* cur = x;
    for (int layer = 0; layer < 3; layer++) {
        k_gemm<<<gemm_grid, 256, 0, stream>>>(cur, theta, G, N_NODES);
        k_attdots<<<wave_blocks, 256, 0, stream>>>(G, att_src, att_dst, a_s, a_d);
        k_aggregate<<<wave_blocks, 256, 0, stream>>>(G, a_s, a_d, offs, deg, esrc, gat_bias, P);
        cur = P;
    }

    // ---- attention pooling + classifier
    k_qp<<<BB, 320, 0, stream>>>(query, attW, qp);
    k_gzero<<<1, 256, 0, stream>>>(gcnt);
    k_gcount<<<NB_SCAN, 256, 0, stream>>>(batch, gcnt);
    k_gscan<<<1, 256, 0, stream>>>(gcnt, goffs);
    k_scores<<<wave_blocks, 256, 0, stream>>>(P, qp, batch, sarr);
    k_pool<<<BB, 256, 0, stream>>>(P, sarr, goffs, gcnt, pr);
    k_linear<<<BB, 256, 0, stream>>>(pr, lin_w, lin_b, out);
}

// Round 2
// 1478.874 us; speedup vs baseline: 1.2150x; 1.2150x over previous
//
#include <hip/hip_runtime.h>
#include <math.h>

#define N_NODES 50000
#define N_EDGES 250000
#define BB      128
#define DD      302
#define QQ      600
#define CC      2000
#define NEG_SLOPE 0.2f

// ---------------------------------------------------------------- CSR build
__global__ void k_deg_init(int* deg, int* cursor) {
    int i = blockIdx.x * blockDim.x + threadIdx.x;
    if (i < N_NODES) { deg[i] = 1; cursor[i] = 0; }  // 1 = self loop
}

__global__ void k_histogram(const int* __restrict__ dst, int* deg) {
    int e = blockIdx.x * blockDim.x + threadIdx.x;
    if (e < N_EDGES) atomicAdd(&deg[dst[e]], 1);
}

__global__ void k_scan_block(const int* __restrict__ deg, int* offs, int* partials) {
    __shared__ int sh[256];
    int i = blockIdx.x * 256 + threadIdx.x;
    int v = (i < N_NODES) ? deg[i] : 0;
    sh[threadIdx.x] = v;
    __syncthreads();
    for (int d = 1; d < 256; d <<= 1) {
        int t = (threadIdx.x >= d) ? sh[threadIdx.x - d] : 0;
        __syncthreads();
        sh[threadIdx.x] += t;
        __syncthreads();
    }
    if (i < N_NODES) offs[i] = sh[threadIdx.x] - v;   // exclusive
    if (threadIdx.x == 255) partials[blockIdx.x] = sh[255];
}

__global__ void k_scan_partials(int* partials, int nb) {
    __shared__ int sh[256];
    int v = (threadIdx.x < nb) ? partials[threadIdx.x] : 0;
    sh[threadIdx.x] = v;
    __syncthreads();
    for (int d = 1; d < 256; d <<= 1) {
        int t = (threadIdx.x >= d) ? sh[threadIdx.x - d] : 0;
        __syncthreads();
        sh[threadIdx.x] += t;
        __syncthreads();
    }
    if (threadIdx.x < nb) partials[threadIdx.x] = sh[threadIdx.x] - v;  // exclusive
}

__global__ void k_scan_add(int* offs, const int* __restrict__ partials) {
    int i = blockIdx.x * 256 + threadIdx.x;
    if (i < N_NODES) offs[i] += partials[blockIdx.x];
}

__global__ void k_scatter(const int* __restrict__ src, const int* __restrict__ dst,
                          const int* __restrict__ offs, int* cursor, int* esrc) {
    int i = blockIdx.x * blockDim.x + threadIdx.x;
    if (i < N_EDGES) {
        int d = dst[i];
        int pos = offs[d] + atomicAdd(&cursor[d], 1);
        esrc[pos] = src[i];
    } else if (i < N_EDGES + N_NODES) {
        int n = i - N_EDGES;
        int pos = offs[n] + atomicAdd(&cursor[n], 1);
        esrc[pos] = n;   // self loop
    }
}

// ---------------------------------------------------------------- tiled SGEMM
// NT: A[M,K], B[N,K] row-major, C[m,n] = sum_k A[m,k]*B[n,k] (+bias[n])
#define BM 64
#define BN 64
#define BK 16
__global__ __launch_bounds__(256) void k_gemm_nt(const float* __restrict__ A,
                                                 const float* __restrict__ B,
                                                 float* __restrict__ C,
                                                 int M, int N, int K,
                                                 const float* __restrict__ bias) {
    __shared__ float As[BK][BM + 4];
    __shared__ float Bs[BK][BN + 4];
    int m0 = blockIdx.y * BM;
    int n0 = blockIdx.x * BN;
    int tid = threadIdx.x;
    int tr = tid >> 4;    // 0..15
    int tc = tid & 15;    // 0..15
    float acc[4][4] = {};
    for (int k0 = 0; k0 < K; k0 += BK) {
        #pragma unroll
        for (int j = 0; j < 4; j++) {
            int e = tid + 256 * j;     // 0..1023
            int r = e >> 4;            // 0..63
            int k = e & 15;
            int gk = k0 + k;
            int gm = m0 + r;
            float va = 0.f;
            if (gm < M && gk < K) va = A[(size_t)gm * K + gk];
            As[k][r] = va;
            int gn = n0 + r;
            float vb = 0.f;
            if (gn < N && gk < K) vb = B[(size_t)gn * K + gk];
            Bs[k][r] = vb;
        }
        __syncthreads();
        #pragma unroll
        for (int k = 0; k < BK; k++) {
            float a[4], b[4];
            #pragma unroll
            for (int i = 0; i < 4; i++) a[i] = As[k][tr * 4 + i];
            #pragma unroll
            for (int j = 0; j < 4; j++) b[j] = Bs[k][tc * 4 + j];
            #pragma unroll
            for (int i = 0; i < 4; i++)
                #pragma unroll
                for (int j = 0; j < 4; j++)
                    acc[i][j] += a[i] * b[j];
        }
        __syncthreads();
    }
    #pragma unroll
    for (int i = 0; i < 4; i++) {
        int gm = m0 + tr * 4 + i;
        if (gm >= M) continue;
        #pragma unroll
        for (int j = 0; j < 4; j++) {
            int gn = n0 + tc * 4 + j;
            if (gn < N) {
                float v = acc[i][j];
                if (bias) v += bias[gn];
                C[(size_t)gm * N + gn] = v;
            }
        }
    }
}

// NN: A[M,K], B[K,N] row-major, C[m,n] = sum_k A[m,k]*B[k,n]
__global__ __launch_bounds__(256) void k_gemm_nn(const float* __restrict__ A,
                                                 const float* __restrict__ B,
                                                 float* __restrict__ C,
                                                 int M, int N, int K) {
    __shared__ float As[BK][BM + 4];
    __shared__ float Bs[BK][BN + 4];
    int m0 = blockIdx.y * BM;
    int n0 = blockIdx.x * BN;
    int tid = threadIdx.x;
    int tr = tid >> 4;
    int tc = tid & 15;
    float acc[4][4] = {};
    for (int k0 = 0; k0 < K; k0 += BK) {
        #pragma unroll
        for (int j = 0; j < 4; j++) {
            int e = tid + 256 * j;
            // A staging: [r over 64 rows][k over 16]
            int r = e >> 4;
            int k = e & 15;
            int gk = k0 + k;
            int gm = m0 + r;
            float va = 0.f;
            if (gm < M && gk < K) va = A[(size_t)gm * K + gk];
            As[k][r] = va;
            // B staging: [k over 16][n over 64], coalesced over n
            int bk = e >> 6;          // 0..15
            int bn = e & 63;          // 0..63
            int gbk = k0 + bk;
            int gbn = n0 + bn;
            float vb = 0.f;
            if (gbk < K && gbn < N) vb = B[(size_t)gbk * N + gbn];
            Bs[bk][bn] = vb;
        }
        __syncthreads();
        #pragma unroll
        for (int k = 0; k < BK; k++) {
            float a[4], b[4];
            #pragma unroll
            for (int i = 0; i < 4; i++) a[i] = As[k][tr * 4 + i];
            #pragma unroll
            for (int j = 0; j < 4; j++) b[j] = Bs[k][tc * 4 + j];
            #pragma unroll
            for (int i = 0; i < 4; i++)
                #pragma unroll
                for (int j = 0; j < 4; j++)
                    acc[i][j] += a[i] * b[j];
        }
        __syncthreads();
    }
    #pragma unroll
    for (int i = 0; i < 4; i++) {
        int gm = m0 + tr * 4 + i;
        if (gm >= M) continue;
        #pragma unroll
        for (int j = 0; j < 4; j++) {
            int gn = n0 + tc * 4 + j;
            if (gn < N) C[(size_t)gm * N + gn] = acc[i][j];
        }
    }
}

// ---------------------------------------------------------------- per-node attention dots
__global__ void k_attdots(const float* __restrict__ h, const float* __restrict__ att_src,
                          const float* __restrict__ att_dst, float* a_s, float* a_d) {
    int gid = blockIdx.x * blockDim.x + threadIdx.x;
    int n = gid >> 6, lane = gid & 63;
    if (n >= N_NODES) return;
    const float* row = h + (size_t)n * DD;
    float ss = 0.f, sd = 0.f;
    for (int j = lane; j < DD; j += 64) {
        float v = row[j];
        ss += v * att_src[j];
        sd += v * att_dst[j];
    }
    for (int off = 32; off; off >>= 1) {
        ss += __shfl_down(ss, off);
        sd += __shfl_down(sd, off);
    }
    if (lane == 0) { a_s[n] = ss; a_d[n] = sd; }
}

// ---------------------------------------------------------------- softmax-aggregate (wave / dst node)
__global__ __launch_bounds__(256) void k_aggregate(const float* __restrict__ h,
                                                   const float* __restrict__ a_s,
                                                   const float* __restrict__ a_d,
                                                   const int* __restrict__ offs,
                                                   const int* __restrict__ deg,
                                                   const int* __restrict__ esrc,
                                                   const float* __restrict__ bias,
                                                   float* __restrict__ out) {
    int gid = blockIdx.x * blockDim.x + threadIdx.x;
    int n = gid >> 6, lane = gid & 63;
    if (n >= N_NODES) return;
    int beg = offs[n], cnt = deg[n];
    float adn = a_d[n];
    // pass 1: max
    float m = -INFINITY;
    for (int i = lane; i < cnt; i += 64) {
        float e = a_s[esrc[beg + i]] + adn;
        e = (e > 0.f) ? e : NEG_SLOPE * e;
        m = fmaxf(m, e);
    }
    for (int off = 32; off; off >>= 1) m = fmaxf(m, __shfl_xor(m, off));
    // pass 2: sum of exp
    float den = 0.f;
    for (int i = lane; i < cnt; i += 64) {
        float e = a_s[esrc[beg + i]] + adn;
        e = (e > 0.f) ? e : NEG_SLOPE * e;
        den += __expf(e - m);
    }
    for (int off = 32; off; off >>= 1) den += __shfl_xor(den, off);
    float inv_den = 1.f / den;
    // pass 3: weighted feature accumulate
    float acc[5] = {0.f, 0.f, 0.f, 0.f, 0.f};
    for (int i = 0; i < cnt; i++) {
        int s = esrc[beg + i];
        float e = a_s[s] + adn;
        e = (e > 0.f) ? e : NEG_SLOPE * e;
        float w = __expf(e - m) * inv_den;
        const float* row = h + (size_t)s * DD;
        #pragma unroll
        for (int j = 0; j < 5; j++) {
            int f = lane + 64 * j;
            if (f < DD) acc[j] += w * row[f];
        }
    }
    #pragma unroll
    for (int j = 0; j < 5; j++) {
        int f = lane + 64 * j;
        if (f < DD) {
            float v = acc[j] + bias[f];
            out[(size_t)n * DD + f] = fmaxf(v, 0.f);   // all 3 layers have trailing relu
        }
    }
}

// ---------------------------------------------------------------- pooling pieces
__global__ void k_gzero(int* gcnt) {
    if (threadIdx.x < BB) gcnt[threadIdx.x] = 0;
}

__global__ void k_gcount(const int* __restrict__ batch, int* gcnt) {
    int i = blockIdx.x * blockDim.x + threadIdx.x;
    if (i < N_NODES) atomicAdd(&gcnt[batch[i]], 1);
}

__global__ void k_gscan(const int* __restrict__ gcnt, int* goffs) {
    __shared__ int sh[BB];
    int t = threadIdx.x;
    if (t < BB) sh[t] = gcnt[t];
    __syncthreads();
    if (t == 0) {
        int run = 0;
        for (int i = 0; i < BB; i++) { int v = sh[i]; sh[i] = run; run += v; }
    }
    __syncthreads();
    if (t < BB) goffs[t] = sh[t];
}

__global__ void k_scores(const float* __restrict__ h, const float* __restrict__ qp,
                         const int* __restrict__ batch, float* sarr) {
    int gid = blockIdx.x * blockDim.x + threadIdx.x;
    int n = gid >> 6, lane = gid & 63;
    if (n >= N_NODES) return;
    const float* row = h + (size_t)n * DD;
    const float* q = qp + (size_t)batch[n] * DD;
    float acc = 0.f;
    for (int j = lane; j < DD; j += 64) acc += row[j] * q[j];
    for (int off = 32; off; off >>= 1) acc += __shfl_down(acc, off);
    if (lane == 0) sarr[n] = acc * 0.04082482904638630f;   // 1/sqrt(600)
}

__global__ __launch_bounds__(256) void k_pool(const float* __restrict__ h,
                                              const float* __restrict__ sarr,
                                              const int* __restrict__ goffs,
                                              const int* __restrict__ gcnt,
                                              float* __restrict__ pooledrelu) {
    int b = blockIdx.x;
    int beg = goffs[b], cnt = gcnt[b];
    __shared__ float red[256];
    // max
    float m = -INFINITY;
    for (int i = threadIdx.x; i < cnt; i += 256) m = fmaxf(m, sarr[beg + i]);
    red[threadIdx.x] = m;
    __syncthreads();
    for (int d = 128; d; d >>= 1) {
        if (threadIdx.x < d) red[threadIdx.x] = fmaxf(red[threadIdx.x], red[threadIdx.x + d]);
        __syncthreads();
    }
    m = red[0];
    __syncthreads();
    // sum exp
    float den = 0.f;
    for (int i = threadIdx.x; i < cnt; i += 256) den += __expf(sarr[beg + i] - m);
    red[threadIdx.x] = den;
    __syncthreads();
    for (int d = 128; d; d >>= 1) {
        if (threadIdx.x < d) red[threadIdx.x] += red[threadIdx.x + d];
        __syncthreads();
    }
    den = red[0];
    float inv = (cnt > 0) ? 1.f / den : 0.f;
    // weighted accumulate
    float acc0 = 0.f, acc1 = 0.f;
    int f0 = threadIdx.x, f1 = threadIdx.x + 256;
    for (int i = 0; i < cnt; i++) {
        float w = __expf(sarr[beg + i] - m) * inv;
        const float* row = h + (size_t)(beg + i) * DD;
        if (f0 < DD) acc0 += w * row[f0];
        if (f1 < DD) acc1 += w * row[f1];
    }
    if (f0 < DD) pooledrelu[(size_t)b * DD + f0] = fmaxf(acc0, 0.f);
    if (f1 < DD) pooledrelu[(size_t)b * DD + f1] = fmaxf(acc1, 0.f);
}

// ---------------------------------------------------------------- launch
extern "C" void kernel_launch(void* const* d_in, const int* in_sizes, int n_in,
                              void* d_out, int out_size, void* d_ws, size_t ws_size,
                              hipStream_t stream) {
    const float* x        = (const float*)d_in[0];
    const int*   edges    = (const int*)d_in[1];   // [2, E]
    const float* query    = (const float*)d_in[2];
    const int*   batch    = (const int*)d_in[3];
    const float* theta    = (const float*)d_in[4];
    const float* att_src  = (const float*)d_in[5];
    const float* att_dst  = (const float*)d_in[6];
    const float* gat_bias = (const float*)d_in[7];
    const float* attW     = (const float*)d_in[8];
    const float* lin_w    = (const float*)d_in[9];
    const float* lin_b    = (const float*)d_in[10];
    float* out = (float*)d_out;

    char* ws = (char*)d_ws;
    size_t off = 0;
    auto alloc = [&](size_t bytes) -> void* {
        off = (off + 255) & ~(size_t)255;
        void* p = ws + off;
        off += bytes;
        return p;
    };

    float* G    = (float*)alloc((size_t)N_NODES * DD * 4);   // gemm output
    float* P    = (float*)alloc((size_t)N_NODES * DD * 4);   // layer output
    float* a_s  = (float*)alloc((size_t)N_NODES * 4);
    float* a_d  = (float*)alloc((size_t)N_NODES * 4);
    float* sarr = (float*)alloc((size_t)N_NODES * 4);
    int* deg    = (int*)alloc((size_t)N_NODES * 4);
    int* cursor = (int*)alloc((size_t)N_NODES * 4);
    int* offs   = (int*)alloc((size_t)N_NODES * 4);
    int* esrc   = (int*)alloc((size_t)(N_EDGES + N_NODES) * 4);
    int* partials = (int*)alloc(256 * 4);
    int* gcnt   = (int*)alloc(BB * 4);
    int* goffs  = (int*)alloc(BB * 4);
    float* qp   = (float*)alloc((size_t)BB * DD * 4);
    float* pr   = (float*)alloc((size_t)BB * DD * 4);

    const int* e_src = edges;
    const int* e_dst = edges + N_EDGES;

    const int NB_SCAN = (N_NODES + 255) / 256;   // 196

    // ---- CSR build (once; edges fixed within a call)
    k_deg_init<<<NB_SCAN, 256, 0, stream>>>(deg, cursor);
    k_histogram<<<(N_EDGES + 255) / 256, 256, 0, stream>>>(e_dst, deg);
    k_scan_block<<<NB_SCAN, 256, 0, stream>>>(deg, offs, partials);
    k_scan_partials<<<1, 256, 0, stream>>>(partials, NB_SCAN);
    k_scan_add<<<NB_SCAN, 256, 0, stream>>>(offs, partials);
    k_scatter<<<(N_EDGES + N_NODES + 255) / 256, 256, 0, stream>>>(e_src, e_dst, offs, cursor, esrc);

    // ---- 3 GAT layers
    dim3 gemm_grid((DD + BN - 1) / BN, (N_NODES + BM - 1) / BM);
    int wave_blocks = (N_NODES + 3) / 4;    // 4 waves / 256-thread block
    const float* cur = x;
    for (int layer = 0; layer < 3; layer++) {
        k_gemm_nt<<<gemm_grid, 256, 0, stream>>>(cur, theta, G, N_NODES, DD, DD, nullptr);
        k_attdots<<<wave_blocks, 256, 0, stream>>>(G, att_src, att_dst, a_s, a_d);
        k_aggregate<<<wave_blocks, 256, 0, stream>>>(G, a_s, a_d, offs, deg, esrc, gat_bias, P);
        cur = P;
    }

    // ---- attention pooling + classifier
    // qp = query @ attW : NN gemm, M=BB, N=DD, K=QQ
    {
        dim3 g((DD + BN - 1) / BN, (BB + BM - 1) / BM);
        k_gemm_nn<<<g, 256, 0, stream>>>(query, attW, qp, BB, DD, QQ);
    }
    k_gzero<<<1, 256, 0, stream>>>(gcnt);
    k_gcount<<<NB_SCAN, 256, 0, stream>>>(batch, gcnt);
    k_gscan<<<1, 256, 0, stream>>>(gcnt, goffs);
    k_scores<<<wave_blocks, 256, 0, stream>>>(P, qp, batch, sarr);
    k_pool<<<BB, 256, 0, stream>>>(P, sarr, goffs, gcnt, pr);
    // out = relu(pooled) @ lin_w^T + lin_b : NT gemm, M=BB, N=CC, K=DD
    {
        dim3 g((CC + BN - 1) / BN, (BB + BM - 1) / BM);
        k_gemm_nt<<<g, 256, 0, stream>>>(pr, lin_w, out, BB, CC, DD, lin_b);
    }
}

// Round 3
// 1410.649 us; speedup vs baseline: 1.2737x; 1.0484x over previous
//
#include <hip/hip_runtime.h>
#include <hip/hip_bf16.h>
#include <math.h>

#define N_NODES 50000
#define N_EDGES 250000
#define BB      128
#define DD      302
#define QQ      600
#define CC      2000
#define NEG_SLOPE 0.2f
#define GS      304        // padded row stride for G and P (16B-aligned rows)
#define KP      320        // padded K (10 x 32)
#define SA      40         // LDS k-stride in shorts (32 + 8 pad)

typedef __attribute__((ext_vector_type(8))) short short8;
typedef __attribute__((ext_vector_type(4))) float f32x4;

// ---------------------------------------------------------------- CSR build
__global__ void k_deg_init(int* deg, int* cursor) {
    int i = blockIdx.x * blockDim.x + threadIdx.x;
    if (i < N_NODES) { deg[i] = 1; cursor[i] = 0; }  // 1 = self loop
}

__global__ void k_histogram(const int* __restrict__ dst, int* deg) {
    int e = blockIdx.x * blockDim.x + threadIdx.x;
    if (e < N_EDGES) atomicAdd(&deg[dst[e]], 1);
}

__global__ void k_scan_block(const int* __restrict__ deg, int* offs, int* partials) {
    __shared__ int sh[256];
    int i = blockIdx.x * 256 + threadIdx.x;
    int v = (i < N_NODES) ? deg[i] : 0;
    sh[threadIdx.x] = v;
    __syncthreads();
    for (int d = 1; d < 256; d <<= 1) {
        int t = (threadIdx.x >= d) ? sh[threadIdx.x - d] : 0;
        __syncthreads();
        sh[threadIdx.x] += t;
        __syncthreads();
    }
    if (i < N_NODES) offs[i] = sh[threadIdx.x] - v;   // exclusive
    if (threadIdx.x == 255) partials[blockIdx.x] = sh[255];
}

__global__ void k_scan_partials(int* partials, int nb) {
    __shared__ int sh[256];
    int v = (threadIdx.x < nb) ? partials[threadIdx.x] : 0;
    sh[threadIdx.x] = v;
    __syncthreads();
    for (int d = 1; d < 256; d <<= 1) {
        int t = (threadIdx.x >= d) ? sh[threadIdx.x - d] : 0;
        __syncthreads();
        sh[threadIdx.x] += t;
        __syncthreads();
    }
    if (threadIdx.x < nb) partials[threadIdx.x] = sh[threadIdx.x] - v;  // exclusive
}

__global__ void k_scan_add(int* offs, const int* __restrict__ partials) {
    int i = blockIdx.x * 256 + threadIdx.x;
    if (i < N_NODES) offs[i] += partials[blockIdx.x];
}

__global__ void k_scatter(const int* __restrict__ src, const int* __restrict__ dst,
                          const int* __restrict__ offs, int* cursor, int* esrc) {
    int i = blockIdx.x * blockDim.x + threadIdx.x;
    if (i < N_EDGES) {
        int d = dst[i];
        int pos = offs[d] + atomicAdd(&cursor[d], 1);
        esrc[pos] = src[i];
    } else if (i < N_EDGES + N_NODES) {
        int n = i - N_EDGES;
        int pos = offs[n] + atomicAdd(&cursor[n], 1);
        esrc[pos] = n;   // self loop
    }
}

// ---------------------------------------------------------------- theta -> padded hi/lo bf16
__global__ void k_theta_prep(const float* __restrict__ theta,
                             unsigned short* __restrict__ thhi,
                             unsigned short* __restrict__ thlo) {
    int idx = blockIdx.x * 256 + threadIdx.x;
    if (idx >= KP * KP) return;
    int n = idx / KP, k = idx % KP;
    float v = (n < DD && k < DD) ? theta[n * DD + k] : 0.f;
    unsigned int u  = __float_as_uint(v);
    unsigned int uh = (u + 0x8000u) & 0xffff0000u;    // round-half-up bf16
    float hf = __uint_as_float(uh);
    float lo = v - hf;
    unsigned int ul = (__float_as_uint(lo) + 0x8000u) >> 16;
    thhi[idx] = (unsigned short)(uh >> 16);
    thlo[idx] = (unsigned short)ul;
}

// ---------------------------------------------------------------- split-bf16 MFMA GEMM
// C[m,n] = sum_k A[m,k] * theta[n,k], A fp32 [M x lda], C fp32 [M x GS]
// A is split to hi/lo bf16 in-kernel; theta pre-split (padded KP x KP).
// Block tile 256(M) x 64(N); 4 waves, each 64x64; 16x16x32 bf16 MFMA; BK=32.
__global__ __launch_bounds__(256) void k_mfma_gemm(const float* __restrict__ A, int lda,
                                                   const unsigned short* __restrict__ Bhg,
                                                   const unsigned short* __restrict__ Blg,
                                                   float* __restrict__ C, int M) {
    __shared__ short Ah[256 * SA];
    __shared__ short Al[256 * SA];
    __shared__ short Bh[64 * SA];
    __shared__ short Bl[64 * SA];

    const int tid  = threadIdx.x;
    const int m0   = blockIdx.y * 256;
    const int n0   = blockIdx.x * 64;
    const int lane = tid & 63;
    const int wave = tid >> 6;
    const int q    = lane >> 4;     // 0..3
    const int mr   = lane & 15;

    f32x4 acc[4][4];
    #pragma unroll
    for (int i = 0; i < 4; i++)
        #pragma unroll
        for (int j = 0; j < 4; j++)
            acc[i][j] = (f32x4){0.f, 0.f, 0.f, 0.f};

    const int   gm    = m0 + tid;            // this thread stages row gm
    const bool  rowok = gm < M;
    const float* arow = A + (size_t)gm * lda;
    const int   brow  = tid >> 2;            // 0..63
    const int   bch   = tid & 3;             // 0..3
    const unsigned short* bhrow = Bhg + (size_t)(n0 + brow) * KP;
    const unsigned short* blrow = Blg + (size_t)(n0 + brow) * KP;

    for (int k0 = 0; k0 < KP; k0 += 32) {
        // ---- stage A: load fp32, split to hi/lo bf16, write LDS
        #pragma unroll
        for (int g = 0; g < 4; g++) {        // 8 floats per group
            float f[8];
            if (lda == GS) {
                float4 v0 = {0.f,0.f,0.f,0.f}, v1 = {0.f,0.f,0.f,0.f};
                if (rowok) {
                    v0 = *(const float4*)(arow + k0 + g * 8);
                    v1 = *(const float4*)(arow + k0 + g * 8 + 4);
                }
                f[0]=v0.x; f[1]=v0.y; f[2]=v0.z; f[3]=v0.w;
                f[4]=v1.x; f[5]=v1.y; f[6]=v1.z; f[7]=v1.w;
            } else {
                #pragma unroll
                for (int p = 0; p < 4; p++) {
                    int k = k0 + g * 8 + p * 2;
                    float2 t = {0.f, 0.f};
                    if (rowok && k < DD) t = *(const float2*)(arow + k);  // DD even: pair never straddles
                    f[p*2] = t.x; f[p*2+1] = t.y;
                }
            }
            unsigned int hp[4], lp[4];
            #pragma unroll
            for (int p = 0; p < 4; p++) {
                float a = f[p*2], b = f[p*2+1];
                __hip_bfloat162 h2 = __float22bfloat162_rn(make_float2(a, b));
                unsigned int hu; __builtin_memcpy(&hu, &h2, 4);
                float ha = __uint_as_float(hu << 16);
                float hb = __uint_as_float(hu & 0xffff0000u);
                __hip_bfloat162 l2 = __float22bfloat162_rn(make_float2(a - ha, b - hb));
                unsigned int lu; __builtin_memcpy(&lu, &l2, 4);
                hp[p] = hu; lp[p] = lu;
            }
            uint4 H = {hp[0], hp[1], hp[2], hp[3]};
            uint4 L = {lp[0], lp[1], lp[2], lp[3]};
            *(uint4*)&Ah[tid * SA + g * 8] = H;
            *(uint4*)&Al[tid * SA + g * 8] = L;
        }
        // ---- stage B (pre-split bf16, 16B per thread per matrix)
        {
            uint4 bh4 = *(const uint4*)(bhrow + k0 + bch * 8);
            uint4 bl4 = *(const uint4*)(blrow + k0 + bch * 8);
            *(uint4*)&Bh[brow * SA + bch * 8] = bh4;
            *(uint4*)&Bl[brow * SA + bch * 8] = bl4;
        }
        __syncthreads();

        // ---- fragments + MFMA
        short8 ah[4], al[4], bhf[4], blf[4];
        #pragma unroll
        for (int mt = 0; mt < 4; mt++) {
            int r = wave * 64 + mt * 16 + mr;
            ah[mt] = *(const short8*)&Ah[r * SA + q * 8];
            al[mt] = *(const short8*)&Al[r * SA + q * 8];
        }
        #pragma unroll
        for (int nt = 0; nt < 4; nt++) {
            int r = nt * 16 + mr;
            bhf[nt] = *(const short8*)&Bh[r * SA + q * 8];
            blf[nt] = *(const short8*)&Bl[r * SA + q * 8];
        }
        #pragma unroll
        for (int mt = 0; mt < 4; mt++)
            #pragma unroll
            for (int nt = 0; nt < 4; nt++) {
                acc[mt][nt] = __builtin_amdgcn_mfma_f32_16x16x32_bf16(ah[mt], bhf[nt], acc[mt][nt], 0, 0, 0);
                acc[mt][nt] = __builtin_amdgcn_mfma_f32_16x16x32_bf16(ah[mt], blf[nt], acc[mt][nt], 0, 0, 0);
                acc[mt][nt] = __builtin_amdgcn_mfma_f32_16x16x32_bf16(al[mt], bhf[nt], acc[mt][nt], 0, 0, 0);
            }
        __syncthreads();
    }

    // ---- epilogue: C/D layout col=lane&15, row=(lane>>4)*4+reg
    #pragma unroll
    for (int mt = 0; mt < 4; mt++) {
        int row_b = m0 + wave * 64 + mt * 16 + q * 4;
        #pragma unroll
        for (int nt = 0; nt < 4; nt++) {
            int col = n0 + nt * 16 + mr;
            if (col >= DD) continue;
            #pragma unroll
            for (int r = 0; r < 4; r++) {
                int row = row_b + r;
                if (row < M) C[(size_t)row * GS + col] = acc[mt][nt][r];
            }
        }
    }
}

// ---------------------------------------------------------------- tiled SGEMM (small matrices)
#define BM 64
#define BN 64
#define BK 16
__global__ __launch_bounds__(256) void k_gemm_nt(const float* __restrict__ A,
                                                 const float* __restrict__ B,
                                                 float* __restrict__ C,
                                                 int M, int N, int K,
                                                 const float* __restrict__ bias) {
    __shared__ float As[BK][BM + 4];
    __shared__ float Bs[BK][BN + 4];
    int m0 = blockIdx.y * BM;
    int n0 = blockIdx.x * BN;
    int tid = threadIdx.x;
    int tr = tid >> 4;
    int tc = tid & 15;
    float acc[4][4] = {};
    for (int k0 = 0; k0 < K; k0 += BK) {
        #pragma unroll
        for (int j = 0; j < 4; j++) {
            int e = tid + 256 * j;
            int r = e >> 4;
            int k = e & 15;
            int gk = k0 + k;
            int gm = m0 + r;
            float va = 0.f;
            if (gm < M && gk < K) va = A[(size_t)gm * K + gk];
            As[k][r] = va;
            int gn = n0 + r;
            float vb = 0.f;
            if (gn < N && gk < K) vb = B[(size_t)gn * K + gk];
            Bs[k][r] = vb;
        }
        __syncthreads();
        #pragma unroll
        for (int k = 0; k < BK; k++) {
            float a[4], b[4];
            #pragma unroll
            for (int i = 0; i < 4; i++) a[i] = As[k][tr * 4 + i];
            #pragma unroll
            for (int j = 0; j < 4; j++) b[j] = Bs[k][tc * 4 + j];
            #pragma unroll
            for (int i = 0; i < 4; i++)
                #pragma unroll
                for (int j = 0; j < 4; j++)
                    acc[i][j] += a[i] * b[j];
        }
        __syncthreads();
    }
    #pragma unroll
    for (int i = 0; i < 4; i++) {
        int gm = m0 + tr * 4 + i;
        if (gm >= M) continue;
        #pragma unroll
        for (int j = 0; j < 4; j++) {
            int gn = n0 + tc * 4 + j;
            if (gn < N) {
                float v = acc[i][j];
                if (bias) v += bias[gn];
                C[(size_t)gm * N + gn] = v;
            }
        }
    }
}

__global__ __launch_bounds__(256) void k_gemm_nn(const float* __restrict__ A,
                                                 const float* __restrict__ B,
                                                 float* __restrict__ C,
                                                 int M, int N, int K) {
    __shared__ float As[BK][BM + 4];
    __shared__ float Bs[BK][BN + 4];
    int m0 = blockIdx.y * BM;
    int n0 = blockIdx.x * BN;
    int tid = threadIdx.x;
    int tr = tid >> 4;
    int tc = tid & 15;
    float acc[4][4] = {};
    for (int k0 = 0; k0 < K; k0 += BK) {
        #pragma unroll
        for (int j = 0; j < 4; j++) {
            int e = tid + 256 * j;
            int r = e >> 4;
            int k = e & 15;
            int gk = k0 + k;
            int gm = m0 + r;
            float va = 0.f;
            if (gm < M && gk < K) va = A[(size_t)gm * K + gk];
            As[k][r] = va;
            int bk = e >> 6;
            int bn = e & 63;
            int gbk = k0 + bk;
            int gbn = n0 + bn;
            float vb = 0.f;
            if (gbk < K && gbn < N) vb = B[(size_t)gbk * N + gbn];
            Bs[bk][bn] = vb;
        }
        __syncthreads();
        #pragma unroll
        for (int k = 0; k < BK; k++) {
            float a[4], b[4];
            #pragma unroll
            for (int i = 0; i < 4; i++) a[i] = As[k][tr * 4 + i];
            #pragma unroll
            for (int j = 0; j < 4; j++) b[j] = Bs[k][tc * 4 + j];
            #pragma unroll
            for (int i = 0; i < 4; i++)
                #pragma unroll
                for (int j = 0; j < 4; j++)
                    acc[i][j] += a[i] * b[j];
        }
        __syncthreads();
    }
    #pragma unroll
    for (int i = 0; i < 4; i++) {
        int gm = m0 + tr * 4 + i;
        if (gm >= M) continue;
        #pragma unroll
        for (int j = 0; j < 4; j++) {
            int gn = n0 + tc * 4 + j;
            if (gn < N) C[(size_t)gm * N + gn] = acc[i][j];
        }
    }
}

// ---------------------------------------------------------------- per-node attention dots
__global__ void k_attdots(const float* __restrict__ h, int ld,
                          const float* __restrict__ att_src,
                          const float* __restrict__ att_dst, float* a_s, float* a_d) {
    int gid = blockIdx.x * blockDim.x + threadIdx.x;
    int n = gid >> 6, lane = gid & 63;
    if (n >= N_NODES) return;
    const float* row = h + (size_t)n * ld;
    float ss = 0.f, sd = 0.f;
    for (int j = lane; j < DD; j += 64) {
        float v = row[j];
        ss += v * att_src[j];
        sd += v * att_dst[j];
    }
    for (int off = 32; off; off >>= 1) {
        ss += __shfl_down(ss, off);
        sd += __shfl_down(sd, off);
    }
    if (lane == 0) { a_s[n] = ss; a_d[n] = sd; }
}

// ---------------------------------------------------------------- softmax-aggregate (wave / dst node)
__global__ __launch_bounds__(256) void k_aggregate(const float* __restrict__ h, int ld,
                                                   const float* __restrict__ a_s,
                                                   const float* __restrict__ a_d,
                                                   const int* __restrict__ offs,
                                                   const int* __restrict__ deg,
                                                   const int* __restrict__ esrc,
                                                   const float* __restrict__ bias,
                                                   float* __restrict__ out) {
    int gid = blockIdx.x * blockDim.x + threadIdx.x;
    int n = gid >> 6, lane = gid & 63;
    if (n >= N_NODES) return;
    int beg = offs[n], cnt = deg[n];
    float adn = a_d[n];
    float m = -INFINITY;
    for (int i = lane; i < cnt; i += 64) {
        float e = a_s[esrc[beg + i]] + adn;
        e = (e > 0.f) ? e : NEG_SLOPE * e;
        m = fmaxf(m, e);
    }
    for (int off = 32; off; off >>= 1) m = fmaxf(m, __shfl_xor(m, off));
    float den = 0.f;
    for (int i = lane; i < cnt; i += 64) {
        float e = a_s[esrc[beg + i]] + adn;
        e = (e > 0.f) ? e : NEG_SLOPE * e;
        den += __expf(e - m);
    }
    for (int off = 32; off; off >>= 1) den += __shfl_xor(den, off);
    float inv_den = 1.f / den;
    float acc[5] = {0.f, 0.f, 0.f, 0.f, 0.f};
    for (int i = 0; i < cnt; i++) {
        int s = esrc[beg + i];
        float e = a_s[s] + adn;
        e = (e > 0.f) ? e : NEG_SLOPE * e;
        float w = __expf(e - m) * inv_den;
        const float* row = h + (size_t)s * ld;
        #pragma unroll
        for (int j = 0; j < 5; j++) {
            int f = lane + 64 * j;
            if (f < DD) acc[j] += w * row[f];
        }
    }
    #pragma unroll
    for (int j = 0; j < 5; j++) {
        int f = lane + 64 * j;
        if (f < DD) {
            float v = acc[j] + bias[f];
            out[(size_t)n * ld + f] = fmaxf(v, 0.f);
        }
    }
    if (lane < GS - DD) out[(size_t)n * ld + DD + lane] = 0.f;  // zero pad cols (staging reads them)
}

// ---------------------------------------------------------------- pooling pieces
__global__ void k_gzero(int* gcnt) {
    if (threadIdx.x < BB) gcnt[threadIdx.x] = 0;
}

__global__ void k_gcount(const int* __restrict__ batch, int* gcnt) {
    int i = blockIdx.x * blockDim.x + threadIdx.x;
    if (i < N_NODES) atomicAdd(&gcnt[batch[i]], 1);
}

__global__ void k_gscan(const int* __restrict__ gcnt, int* goffs) {
    __shared__ int sh[BB];
    int t = threadIdx.x;
    if (t < BB) sh[t] = gcnt[t];
    __syncthreads();
    if (t == 0) {
        int run = 0;
        for (int i = 0; i < BB; i++) { int v = sh[i]; sh[i] = run; run += v; }
    }
    __syncthreads();
    if (t < BB) goffs[t] = sh[t];
}

__global__ void k_scores(const float* __restrict__ h, int ld,
                         const float* __restrict__ qp,
                         const int* __restrict__ batch, float* sarr) {
    int gid = blockIdx.x * blockDim.x + threadIdx.x;
    int n = gid >> 6, lane = gid & 63;
    if (n >= N_NODES) return;
    const float* row = h + (size_t)n * ld;
    const float* q = qp + (size_t)batch[n] * DD;
    float acc = 0.f;
    for (int j = lane; j < DD; j += 64) acc += row[j] * q[j];
    for (int off = 32; off; off >>= 1) acc += __shfl_down(acc, off);
    if (lane == 0) sarr[n] = acc * 0.04082482904638630f;   // 1/sqrt(600)
}

__global__ __launch_bounds__(256) void k_pool(const float* __restrict__ h, int ld,
                                              const float* __restrict__ sarr,
                                              const int* __restrict__ goffs,
                                              const int* __restrict__ gcnt,
                                              float* __restrict__ pooledrelu) {
    int b = blockIdx.x;
    int beg = goffs[b], cnt = gcnt[b];
    __shared__ float red[256];
    float m = -INFINITY;
    for (int i = threadIdx.x; i < cnt; i += 256) m = fmaxf(m, sarr[beg + i]);
    red[threadIdx.x] = m;
    __syncthreads();
    for (int d = 128; d; d >>= 1) {
        if (threadIdx.x < d) red[threadIdx.x] = fmaxf(red[threadIdx.x], red[threadIdx.x + d]);
        __syncthreads();
    }
    m = red[0];
    __syncthreads();
    float den = 0.f;
    for (int i = threadIdx.x; i < cnt; i += 256) den += __expf(sarr[beg + i] - m);
    red[threadIdx.x] = den;
    __syncthreads();
    for (int d = 128; d; d >>= 1) {
        if (threadIdx.x < d) red[threadIdx.x] += red[threadIdx.x + d];
        __syncthreads();
    }
    den = red[0];
    float inv = (cnt > 0) ? 1.f / den : 0.f;
    float acc0 = 0.f, acc1 = 0.f;
    int f0 = threadIdx.x, f1 = threadIdx.x + 256;
    for (int i = 0; i < cnt; i++) {
        float w = __expf(sarr[beg + i] - m) * inv;
        const float* row = h + (size_t)(beg + i) * ld;
        if (f0 < DD) acc0 += w * row[f0];
        if (f1 < DD) acc1 += w * row[f1];
    }
    if (f0 < DD) pooledrelu[(size_t)b * DD + f0] = fmaxf(acc0, 0.f);
    if (f1 < DD) pooledrelu[(size_t)b * DD + f1] = fmaxf(acc1, 0.f);
}

// ---------------------------------------------------------------- launch
extern "C" void kernel_launch(void* const* d_in, const int* in_sizes, int n_in,
                              void* d_out, int out_size, void* d_ws, size_t ws_size,
                              hipStream_t stream) {
    const float* x        = (const float*)d_in[0];
    const int*   edges    = (const int*)d_in[1];   // [2, E]
    const float* query    = (const float*)d_in[2];
    const int*   batch    = (const int*)d_in[3];
    const float* theta    = (const float*)d_in[4];
    const float* att_src  = (const float*)d_in[5];
    const float* att_dst  = (const float*)d_in[6];
    const float* gat_bias = (const float*)d_in[7];
    const float* attW     = (const float*)d_in[8];
    const float* lin_w    = (const float*)d_in[9];
    const float* lin_b    = (const float*)d_in[10];
    float* out = (float*)d_out;

    char* ws = (char*)d_ws;
    size_t off = 0;
    auto alloc = [&](size_t bytes) -> void* {
        off = (off + 255) & ~(size_t)255;
        void* p = ws + off;
        off += bytes;
        return p;
    };

    float* G    = (float*)alloc((size_t)N_NODES * GS * 4);   // gemm output (padded stride)
    float* P    = (float*)alloc((size_t)N_NODES * GS * 4);   // layer output (padded stride)
    unsigned short* thhi = (unsigned short*)alloc((size_t)KP * KP * 2);
    unsigned short* thlo = (unsigned short*)alloc((size_t)KP * KP * 2);
    float* a_s  = (float*)alloc((size_t)N_NODES * 4);
    float* a_d  = (float*)alloc((size_t)N_NODES * 4);
    float* sarr = (float*)alloc((size_t)N_NODES * 4);
    int* deg    = (int*)alloc((size_t)N_NODES * 4);
    int* cursor = (int*)alloc((size_t)N_NODES * 4);
    int* offs   = (int*)alloc((size_t)N_NODES * 4);
    int* esrc   = (int*)alloc((size_t)(N_EDGES + N_NODES) * 4);
    int* partials = (int*)alloc(256 * 4);
    int* gcnt   = (int*)alloc(BB * 4);
    int* goffs  = (int*)alloc(BB * 4);
    float* qp   = (float*)alloc((size_t)BB * DD * 4);
    float* pr   = (float*)alloc((size_t)BB * DD * 4);

    const int* e_src = edges;
    const int* e_dst = edges + N_EDGES;

    const int NB_SCAN = (N_NODES + 255) / 256;   // 196

    // ---- CSR build
    k_deg_init<<<NB_SCAN, 256, 0, stream>>>(deg, cursor);
    k_histogram<<<(N_EDGES + 255) / 256, 256, 0, stream>>>(e_dst, deg);
    k_scan_block<<<NB_SCAN, 256, 0, stream>>>(deg, offs, partials);
    k_scan_partials<<<1, 256, 0, stream>>>(partials, NB_SCAN);
    k_scan_add<<<NB_SCAN, 256, 0, stream>>>(offs, partials);
    k_scatter<<<(N_EDGES + N_NODES + 255) / 256, 256, 0, stream>>>(e_src, e_dst, offs, cursor, esrc);

    // ---- theta hi/lo split (once; shared across layers)
    k_theta_prep<<<(KP * KP + 255) / 256, 256, 0, stream>>>(theta, thhi, thlo);

    // ---- 3 GAT layers
    dim3 mfma_grid((KP / 64), (N_NODES + 255) / 256);   // 5 x 196
    int wave_blocks = (N_NODES + 3) / 4;
    const float* cur = x;
    int cur_ld = DD;
    for (int layer = 0; layer < 3; layer++) {
        k_mfma_gemm<<<mfma_grid, 256, 0, stream>>>(cur, cur_ld, thhi, thlo, G, N_NODES);
        k_attdots<<<wave_blocks, 256, 0, stream>>>(G, GS, att_src, att_dst, a_s, a_d);
        k_aggregate<<<wave_blocks, 256, 0, stream>>>(G, GS, a_s, a_d, offs, deg, esrc, gat_bias, P);
        cur = P;
        cur_ld = GS;
    }

    // ---- attention pooling + classifier
    {
        dim3 g((DD + BN - 1) / BN, (BB + BM - 1) / BM);
        k_gemm_nn<<<g, 256, 0, stream>>>(query, attW, qp, BB, DD, QQ);
    }
    k_gzero<<<1, 256, 0, stream>>>(gcnt);
    k_gcount<<<NB_SCAN, 256, 0, stream>>>(batch, gcnt);
    k_gscan<<<1, 256, 0, stream>>>(gcnt, goffs);
    k_scores<<<wave_blocks, 256, 0, stream>>>(P, GS, qp, batch, sarr);
    k_pool<<<BB, 256, 0, stream>>>(P, GS, sarr, goffs, gcnt, pr);
    {
        dim3 g((CC + BN - 1) / BN, (BB + BM - 1) / BM);
        k_gemm_nt<<<g, 256, 0, stream>>>(pr, lin_w, out, BB, CC, DD, lin_b);
    }
}

// Round 4
// 1105.541 us; speedup vs baseline: 1.6252x; 1.2760x over previous
//
#include <hip/hip_runtime.h>
#include <hip/hip_bf16.h>
#include <math.h>

#define N_NODES 50000
#define N_EDGES 250000
#define BB      128
#define DD      302
#define QQ      600
#define CC      2000
#define NEG_SLOPE 0.2f
#define GS      304        // padded row stride for G and P (16B-aligned rows)
#define KP      320        // padded K (10 x 32)
#define SA      40         // LDS k-stride in shorts (32 + 8 pad)
#define KSTEPS  10         // KP / 32

typedef __attribute__((ext_vector_type(8))) short short8;
typedef __attribute__((ext_vector_type(4))) float f32x4;

// ---------------------------------------------------------------- CSR build
__global__ void k_deg_init(int* deg, int* cursor) {
    int i = blockIdx.x * blockDim.x + threadIdx.x;
    if (i < N_NODES) { deg[i] = 1; cursor[i] = 0; }  // 1 = self loop
}

__global__ void k_histogram(const int* __restrict__ dst, int* deg) {
    int e = blockIdx.x * blockDim.x + threadIdx.x;
    if (e < N_EDGES) atomicAdd(&deg[dst[e]], 1);
}

__global__ void k_scan_block(const int* __restrict__ deg, int* offs, int* partials) {
    __shared__ int sh[256];
    int i = blockIdx.x * 256 + threadIdx.x;
    int v = (i < N_NODES) ? deg[i] : 0;
    sh[threadIdx.x] = v;
    __syncthreads();
    for (int d = 1; d < 256; d <<= 1) {
        int t = (threadIdx.x >= d) ? sh[threadIdx.x - d] : 0;
        __syncthreads();
        sh[threadIdx.x] += t;
        __syncthreads();
    }
    if (i < N_NODES) offs[i] = sh[threadIdx.x] - v;   // exclusive
    if (threadIdx.x == 255) partials[blockIdx.x] = sh[255];
}

__global__ void k_scan_partials(int* partials, int nb) {
    __shared__ int sh[256];
    int v = (threadIdx.x < nb) ? partials[threadIdx.x] : 0;
    sh[threadIdx.x] = v;
    __syncthreads();
    for (int d = 1; d < 256; d <<= 1) {
        int t = (threadIdx.x >= d) ? sh[threadIdx.x - d] : 0;
        __syncthreads();
        sh[threadIdx.x] += t;
        __syncthreads();
    }
    if (threadIdx.x < nb) partials[threadIdx.x] = sh[threadIdx.x] - v;  // exclusive
}

__global__ void k_scan_add(int* offs, const int* __restrict__ partials) {
    int i = blockIdx.x * 256 + threadIdx.x;
    if (i < N_NODES) offs[i] += partials[blockIdx.x];
}

__global__ void k_scatter(const int* __restrict__ src, const int* __restrict__ dst,
                          const int* __restrict__ offs, int* cursor, int* esrc) {
    int i = blockIdx.x * blockDim.x + threadIdx.x;
    if (i < N_EDGES) {
        int d = dst[i];
        int pos = offs[d] + atomicAdd(&cursor[d], 1);
        esrc[pos] = src[i];
    } else if (i < N_EDGES + N_NODES) {
        int n = i - N_EDGES;
        int pos = offs[n] + atomicAdd(&cursor[n], 1);
        esrc[pos] = n;   // self loop
    }
}

// ---------------------------------------------------------------- theta -> padded hi/lo bf16
__global__ void k_theta_prep(const float* __restrict__ theta,
                             unsigned short* __restrict__ thhi,
                             unsigned short* __restrict__ thlo) {
    int idx = blockIdx.x * 256 + threadIdx.x;
    if (idx >= KP * KP) return;
    int n = idx / KP, k = idx % KP;
    float v = (n < DD && k < DD) ? theta[n * DD + k] : 0.f;
    unsigned int u  = __float_as_uint(v);
    unsigned int uh = (u + 0x8000u) & 0xffff0000u;    // round-half-up bf16
    float hf = __uint_as_float(uh);
    float lo = v - hf;
    unsigned int ul = (__float_as_uint(lo) + 0x8000u) >> 16;
    thhi[idx] = (unsigned short)(uh >> 16);
    thlo[idx] = (unsigned short)ul;
}

// ---------------------------------------------------------------- split-bf16 MFMA GEMM
// C[m,n] = sum_k A[m,k] * theta[n,k]; A fp32 [M x lda], C fp32 [M x GS].
// Block: 64 rows x full N (320). 4 waves, each 64(m) x 80(n) = 4x5 MFMA tiles.
// A hi/lo split in-kernel, staged in LDS double-buffered (1 barrier/k-step).
// B (theta) pre-split hi/lo, read as fragments directly from global (L2-hot, 400KB).
__global__ __launch_bounds__(256) void k_mfma_gemm(const float* __restrict__ A, int lda,
                                                   const unsigned short* __restrict__ Bhg,
                                                   const unsigned short* __restrict__ Blg,
                                                   float* __restrict__ C, int M) {
    __shared__ short Ah[2][64 * SA];
    __shared__ short Al[2][64 * SA];

    const int tid   = threadIdx.x;
    const int m0    = blockIdx.x * 64;
    const int lane  = tid & 63;
    const int wave  = tid >> 6;         // 0..3
    const int q     = lane >> 4;        // 0..3
    const int mr    = lane & 15;
    const int nbase = wave * 80;

    f32x4 acc[4][5];
    #pragma unroll
    for (int i = 0; i < 4; i++)
        #pragma unroll
        for (int j = 0; j < 5; j++)
            acc[i][j] = (f32x4){0.f, 0.f, 0.f, 0.f};

    // staging assignment: thread t stages row t>>2, k-chunk (t&3)*8
    const int  srow  = tid >> 2;        // 0..63
    const int  schk  = tid & 3;         // 0..3
    const bool rowok = (m0 + srow) < M;
    const float* arow = A + (size_t)(m0 + srow) * lda;

    float fst[8];
    auto load_stage = [&](int k0) {
        if (lda == GS) {
            float4 v0 = {0.f,0.f,0.f,0.f}, v1 = {0.f,0.f,0.f,0.f};
            if (rowok) {
                v0 = *(const float4*)(arow + k0 + schk * 8);
                v1 = *(const float4*)(arow + k0 + schk * 8 + 4);
            }
            fst[0]=v0.x; fst[1]=v0.y; fst[2]=v0.z; fst[3]=v0.w;
            fst[4]=v1.x; fst[5]=v1.y; fst[6]=v1.z; fst[7]=v1.w;
        } else {
            #pragma unroll
            for (int p = 0; p < 4; p++) {
                int k = k0 + schk * 8 + p * 2;
                float2 t = {0.f, 0.f};
                if (rowok && k < DD) t = *(const float2*)(arow + k);  // DD even
                fst[p*2] = t.x; fst[p*2+1] = t.y;
            }
        }
    };
    auto write_stage = [&](int buf) {
        unsigned int hp[4], lp[4];
        #pragma unroll
        for (int p = 0; p < 4; p++) {
            float a = fst[p*2], b = fst[p*2+1];
            __hip_bfloat162 h2 = __float22bfloat162_rn(make_float2(a, b));
            unsigned int hu; __builtin_memcpy(&hu, &h2, 4);
            float ha = __uint_as_float(hu << 16);
            float hb = __uint_as_float(hu & 0xffff0000u);
            __hip_bfloat162 l2 = __float22bfloat162_rn(make_float2(a - ha, b - hb));
            unsigned int lu; __builtin_memcpy(&lu, &l2, 4);
            hp[p] = hu; lp[p] = lu;
        }
        uint4 H = {hp[0], hp[1], hp[2], hp[3]};
        uint4 L = {lp[0], lp[1], lp[2], lp[3]};
        *(uint4*)&Ah[buf][srow * SA + schk * 8] = H;
        *(uint4*)&Al[buf][srow * SA + schk * 8] = L;
    };

    load_stage(0);
    write_stage(0);
    __syncthreads();

    for (int ks = 0; ks < KSTEPS; ks++) {
        const int cur = ks & 1;
        const int k0  = ks * 32;
        if (ks + 1 < KSTEPS) load_stage(k0 + 32);     // issue early; consumed after MFMA

        // B fragments for this k-panel (global, L2-hot)
        short8 bh[5], bl[5];
        #pragma unroll
        for (int nt = 0; nt < 5; nt++) {
            size_t boff = (size_t)(nbase + nt * 16 + mr) * KP + k0 + q * 8;
            bh[nt] = *(const short8*)(Bhg + boff);
            bl[nt] = *(const short8*)(Blg + boff);
        }
        // A fragments from LDS
        short8 ah[4], al[4];
        #pragma unroll
        for (int mt = 0; mt < 4; mt++) {
            ah[mt] = *(const short8*)&Ah[cur][(mt * 16 + mr) * SA + q * 8];
            al[mt] = *(const short8*)&Al[cur][(mt * 16 + mr) * SA + q * 8];
        }
        #pragma unroll
        for (int mt = 0; mt < 4; mt++)
            #pragma unroll
            for (int nt = 0; nt < 5; nt++) {
                acc[mt][nt] = __builtin_amdgcn_mfma_f32_16x16x32_bf16(ah[mt], bh[nt], acc[mt][nt], 0, 0, 0);
                acc[mt][nt] = __builtin_amdgcn_mfma_f32_16x16x32_bf16(ah[mt], bl[nt], acc[mt][nt], 0, 0, 0);
                acc[mt][nt] = __builtin_amdgcn_mfma_f32_16x16x32_bf16(al[mt], bh[nt], acc[mt][nt], 0, 0, 0);
            }

        if (ks + 1 < KSTEPS) write_stage(cur ^ 1);    // other buffer: safe pre-barrier
        __syncthreads();
    }

    // epilogue: C/D layout col=lane&15, row=(lane>>4)*4+reg
    #pragma unroll
    for (int mt = 0; mt < 4; mt++) {
        int row_b = m0 + mt * 16 + q * 4;
        #pragma unroll
        for (int nt = 0; nt < 5; nt++) {
            int col = nbase + nt * 16 + mr;
            if (col >= DD) continue;
            #pragma unroll
            for (int r = 0; r < 4; r++) {
                int row = row_b + r;
                if (row < M) C[(size_t)row * GS + col] = acc[mt][nt][r];
            }
        }
    }
}

// ---------------------------------------------------------------- tiled SGEMM (small matrices)
#define BM 64
#define BN 64
#define BK 16
__global__ __launch_bounds__(256) void k_gemm_nt(const float* __restrict__ A,
                                                 const float* __restrict__ B,
                                                 float* __restrict__ C,
                                                 int M, int N, int K,
                                                 const float* __restrict__ bias) {
    __shared__ float As[BK][BM + 4];
    __shared__ float Bs[BK][BN + 4];
    int m0 = blockIdx.y * BM;
    int n0 = blockIdx.x * BN;
    int tid = threadIdx.x;
    int tr = tid >> 4;
    int tc = tid & 15;
    float acc[4][4] = {};
    for (int k0 = 0; k0 < K; k0 += BK) {
        #pragma unroll
        for (int j = 0; j < 4; j++) {
            int e = tid + 256 * j;
            int r = e >> 4;
            int k = e & 15;
            int gk = k0 + k;
            int gm = m0 + r;
            float va = 0.f;
            if (gm < M && gk < K) va = A[(size_t)gm * K + gk];
            As[k][r] = va;
            int gn = n0 + r;
            float vb = 0.f;
            if (gn < N && gk < K) vb = B[(size_t)gn * K + gk];
            Bs[k][r] = vb;
        }
        __syncthreads();
        #pragma unroll
        for (int k = 0; k < BK; k++) {
            float a[4], b[4];
            #pragma unroll
            for (int i = 0; i < 4; i++) a[i] = As[k][tr * 4 + i];
            #pragma unroll
            for (int j = 0; j < 4; j++) b[j] = Bs[k][tc * 4 + j];
            #pragma unroll
            for (int i = 0; i < 4; i++)
                #pragma unroll
                for (int j = 0; j < 4; j++)
                    acc[i][j] += a[i] * b[j];
        }
        __syncthreads();
    }
    #pragma unroll
    for (int i = 0; i < 4; i++) {
        int gm = m0 + tr * 4 + i;
        if (gm >= M) continue;
        #pragma unroll
        for (int j = 0; j < 4; j++) {
            int gn = n0 + tc * 4 + j;
            if (gn < N) {
                float v = acc[i][j];
                if (bias) v += bias[gn];
                C[(size_t)gm * N + gn] = v;
            }
        }
    }
}

__global__ __launch_bounds__(256) void k_gemm_nn(const float* __restrict__ A,
                                                 const float* __restrict__ B,
                                                 float* __restrict__ C,
                                                 int M, int N, int K) {
    __shared__ float As[BK][BM + 4];
    __shared__ float Bs[BK][BN + 4];
    int m0 = blockIdx.y * BM;
    int n0 = blockIdx.x * BN;
    int tid = threadIdx.x;
    int tr = tid >> 4;
    int tc = tid & 15;
    float acc[4][4] = {};
    for (int k0 = 0; k0 < K; k0 += BK) {
        #pragma unroll
        for (int j = 0; j < 4; j++) {
            int e = tid + 256 * j;
            int r = e >> 4;
            int k = e & 15;
            int gk = k0 + k;
            int gm = m0 + r;
            float va = 0.f;
            if (gm < M && gk < K) va = A[(size_t)gm * K + gk];
            As[k][r] = va;
            int bk = e >> 6;
            int bn = e & 63;
            int gbk = k0 + bk;
            int gbn = n0 + bn;
            float vb = 0.f;
            if (gbk < K && gbn < N) vb = B[(size_t)gbk * N + gbn];
            Bs[bk][bn] = vb;
        }
        __syncthreads();
        #pragma unroll
        for (int k = 0; k < BK; k++) {
            float a[4], b[4];
            #pragma unroll
            for (int i = 0; i < 4; i++) a[i] = As[k][tr * 4 + i];
            #pragma unroll
            for (int j = 0; j < 4; j++) b[j] = Bs[k][tc * 4 + j];
            #pragma unroll
            for (int i = 0; i < 4; i++)
                #pragma unroll
                for (int j = 0; j < 4; j++)
                    acc[i][j] += a[i] * b[j];
        }
        __syncthreads();
    }
    #pragma unroll
    for (int i = 0; i < 4; i++) {
        int gm = m0 + tr * 4 + i;
        if (gm >= M) continue;
        #pragma unroll
        for (int j = 0; j < 4; j++) {
            int gn = n0 + tc * 4 + j;
            if (gn < N) C[(size_t)gm * N + gn] = acc[i][j];
        }
    }
}

// ---------------------------------------------------------------- per-node attention dots
__global__ void k_attdots(const float* __restrict__ h, int ld,
                          const float* __restrict__ att_src,
                          const float* __restrict__ att_dst, float* a_s, float* a_d) {
    int gid = blockIdx.x * blockDim.x + threadIdx.x;
    int n = gid >> 6, lane = gid & 63;
    if (n >= N_NODES) return;
    const float* row = h + (size_t)n * ld;
    float ss = 0.f, sd = 0.f;
    for (int j = lane; j < DD; j += 64) {
        float v = row[j];
        ss += v * att_src[j];
        sd += v * att_dst[j];
    }
    for (int off = 32; off; off >>= 1) {
        ss += __shfl_down(ss, off);
        sd += __shfl_down(sd, off);
    }
    if (lane == 0) { a_s[n] = ss; a_d[n] = sd; }
}

// ---------------------------------------------------------------- softmax-aggregate (wave / dst node)
__global__ __launch_bounds__(256) void k_aggregate(const float* __restrict__ h, int ld,
                                                   const float* __restrict__ a_s,
                                                   const float* __restrict__ a_d,
                                                   const int* __restrict__ offs,
                                                   const int* __restrict__ deg,
                                                   const int* __restrict__ esrc,
                                                   const float* __restrict__ bias,
                                                   float* __restrict__ out) {
    int gid = blockIdx.x * blockDim.x + threadIdx.x;
    int n = gid >> 6, lane = gid & 63;
    if (n >= N_NODES) return;
    int beg = offs[n], cnt = deg[n];
    float adn = a_d[n];
    float m = -INFINITY;
    for (int i = lane; i < cnt; i += 64) {
        float e = a_s[esrc[beg + i]] + adn;
        e = (e > 0.f) ? e : NEG_SLOPE * e;
        m = fmaxf(m, e);
    }
    for (int off = 32; off; off >>= 1) m = fmaxf(m, __shfl_xor(m, off));
    float den = 0.f;
    for (int i = lane; i < cnt; i += 64) {
        float e = a_s[esrc[beg + i]] + adn;
        e = (e > 0.f) ? e : NEG_SLOPE * e;
        den += __expf(e - m);
    }
    for (int off = 32; off; off >>= 1) den += __shfl_xor(den, off);
    float inv_den = 1.f / den;
    float acc[5] = {0.f, 0.f, 0.f, 0.f, 0.f};
    for (int i = 0; i < cnt; i++) {
        int s = esrc[beg + i];
        float e = a_s[s] + adn;
        e = (e > 0.f) ? e : NEG_SLOPE * e;
        float w = __expf(e - m) * inv_den;
        const float* row = h + (size_t)s * ld;
        #pragma unroll
        for (int j = 0; j < 5; j++) {
            int f = lane + 64 * j;
            if (f < DD) acc[j] += w * row[f];
        }
    }
    #pragma unroll
    for (int j = 0; j < 5; j++) {
        int f = lane + 64 * j;
        if (f < DD) {
            float v = acc[j] + bias[f];
            out[(size_t)n * ld + f] = fmaxf(v, 0.f);
        }
    }
    if (lane < GS - DD) out[(size_t)n * ld + DD + lane] = 0.f;  // zero pad cols
}

// ---------------------------------------------------------------- pooling pieces
__global__ void k_gzero(int* gcnt) {
    if (threadIdx.x < BB) gcnt[threadIdx.x] = 0;
}

__global__ void k_gcount(const int* __restrict__ batch, int* gcnt) {
    int i = blockIdx.x * blockDim.x + threadIdx.x;
    if (i < N_NODES) atomicAdd(&gcnt[batch[i]], 1);
}

__global__ void k_gscan(const int* __restrict__ gcnt, int* goffs) {
    __shared__ int sh[BB];
    int t = threadIdx.x;
    if (t < BB) sh[t] = gcnt[t];
    __syncthreads();
    if (t == 0) {
        int run = 0;
        for (int i = 0; i < BB; i++) { int v = sh[i]; sh[i] = run; run += v; }
    }
    __syncthreads();
    if (t < BB) goffs[t] = sh[t];
}

__global__ void k_scores(const float* __restrict__ h, int ld,
                         const float* __restrict__ qp,
                         const int* __restrict__ batch, float* sarr) {
    int gid = blockIdx.x * blockDim.x + threadIdx.x;
    int n = gid >> 6, lane = gid & 63;
    if (n >= N_NODES) return;
    const float* row = h + (size_t)n * ld;
    const float* q = qp + (size_t)batch[n] * DD;
    float acc = 0.f;
    for (int j = lane; j < DD; j += 64) acc += row[j] * q[j];
    for (int off = 32; off; off >>= 1) acc += __shfl_down(acc, off);
    if (lane == 0) sarr[n] = acc * 0.04082482904638630f;   // 1/sqrt(600)
}

__global__ __launch_bounds__(256) void k_pool(const float* __restrict__ h, int ld,
                                              const float* __restrict__ sarr,
                                              const int* __restrict__ goffs,
                                              const int* __restrict__ gcnt,
                                              float* __restrict__ pooledrelu) {
    int b = blockIdx.x;
    int beg = goffs[b], cnt = gcnt[b];
    __shared__ float red[256];
    float m = -INFINITY;
    for (int i = threadIdx.x; i < cnt; i += 256) m = fmaxf(m, sarr[beg + i]);
    red[threadIdx.x] = m;
    __syncthreads();
    for (int d = 128; d; d >>= 1) {
        if (threadIdx.x < d) red[threadIdx.x] = fmaxf(red[threadIdx.x], red[threadIdx.x + d]);
        __syncthreads();
    }
    m = red[0];
    __syncthreads();
    float den = 0.f;
    for (int i = threadIdx.x; i < cnt; i += 256) den += __expf(sarr[beg + i] - m);
    red[threadIdx.x] = den;
    __syncthreads();
    for (int d = 128; d; d >>= 1) {
        if (threadIdx.x < d) red[threadIdx.x] += red[threadIdx.x + d];
        __syncthreads();
    }
    den = red[0];
    float inv = (cnt > 0) ? 1.f / den : 0.f;
    float acc0 = 0.f, acc1 = 0.f;
    int f0 = threadIdx.x, f1 = threadIdx.x + 256;
    for (int i = 0; i < cnt; i++) {
        float w = __expf(sarr[beg + i] - m) * inv;
        const float* row = h + (size_t)(beg + i) * ld;
        if (f0 < DD) acc0 += w * row[f0];
        if (f1 < DD) acc1 += w * row[f1];
    }
    if (f0 < DD) pooledrelu[(size_t)b * DD + f0] = fmaxf(acc0, 0.f);
    if (f1 < DD) pooledrelu[(size_t)b * DD + f1] = fmaxf(acc1, 0.f);
}

// ---------------------------------------------------------------- launch
extern "C" void kernel_launch(void* const* d_in, const int* in_sizes, int n_in,
                              void* d_out, int out_size, void* d_ws, size_t ws_size,
                              hipStream_t stream) {
    const float* x        = (const float*)d_in[0];
    const int*   edges    = (const int*)d_in[1];   // [2, E]
    const float* query    = (const float*)d_in[2];
    const int*   batch    = (const int*)d_in[3];
    const float* theta    = (const float*)d_in[4];
    const float* att_src  = (const float*)d_in[5];
    const float* att_dst  = (const float*)d_in[6];
    const float* gat_bias = (const float*)d_in[7];
    const float* attW     = (const float*)d_in[8];
    const float* lin_w    = (const float*)d_in[9];
    const float* lin_b    = (const float*)d_in[10];
    float* out = (float*)d_out;

    char* ws = (char*)d_ws;
    size_t off = 0;
    auto alloc = [&](size_t bytes) -> void* {
        off = (off + 255) & ~(size_t)255;
        void* p = ws + off;
        off += bytes;
        return p;
    };

    float* G    = (float*)alloc((size_t)N_NODES * GS * 4);   // gemm output (padded stride)
    float* P    = (float*)alloc((size_t)N_NODES * GS * 4);   // layer output (padded stride)
    unsigned short* thhi = (unsigned short*)alloc((size_t)KP * KP * 2);
    unsigned short* thlo = (unsigned short*)alloc((size_t)KP * KP * 2);
    float* a_s  = (float*)alloc((size_t)N_NODES * 4);
    float* a_d  = (float*)alloc((size_t)N_NODES * 4);
    float* sarr = (float*)alloc((size_t)N_NODES * 4);
    int* deg    = (int*)alloc((size_t)N_NODES * 4);
    int* cursor = (int*)alloc((size_t)N_NODES * 4);
    int* offs   = (int*)alloc((size_t)N_NODES * 4);
    int* esrc   = (int*)alloc((size_t)(N_EDGES + N_NODES) * 4);
    int* partials = (int*)alloc(256 * 4);
    int* gcnt   = (int*)alloc(BB * 4);
    int* goffs  = (int*)alloc(BB * 4);
    float* qp   = (float*)alloc((size_t)BB * DD * 4);
    float* pr   = (float*)alloc((size_t)BB * DD * 4);

    const int* e_src = edges;
    const int* e_dst = edges + N_EDGES;

    const int NB_SCAN = (N_NODES + 255) / 256;   // 196

    // ---- CSR build
    k_deg_init<<<NB_SCAN, 256, 0, stream>>>(deg, cursor);
    k_histogram<<<(N_EDGES + 255) / 256, 256, 0, stream>>>(e_dst, deg);
    k_scan_block<<<NB_SCAN, 256, 0, stream>>>(deg, offs, partials);
    k_scan_partials<<<1, 256, 0, stream>>>(partials, NB_SCAN);
    k_scan_add<<<NB_SCAN, 256, 0, stream>>>(offs, partials);
    k_scatter<<<(N_EDGES + N_NODES + 255) / 256, 256, 0, stream>>>(e_src, e_dst, offs, cursor, esrc);

    // ---- theta hi/lo split (once; shared across layers)
    k_theta_prep<<<(KP * KP + 255) / 256, 256, 0, stream>>>(theta, thhi, thlo);

    // ---- 3 GAT layers
    int mfma_blocks = (N_NODES + 63) / 64;   // 782
    int wave_blocks = (N_NODES + 3) / 4;
    const float* cur = x;
    int cur_ld = DD;
    for (int layer = 0; layer < 3; layer++) {
        k_mfma_gemm<<<mfma_blocks, 256, 0, stream>>>(cur, cur_ld, thhi, thlo, G, N_NODES);
        k_attdots<<<wave_blocks, 256, 0, stream>>>(G, GS, att_src, att_dst, a_s, a_d);
        k_aggregate<<<wave_blocks, 256, 0, stream>>>(G, GS, a_s, a_d, offs, deg, esrc, gat_bias, P);
        cur = P;
        cur_ld = GS;
    }

    // ---- attention pooling + classifier
    {
        dim3 g((DD + BN - 1) / BN, (BB + BM - 1) / BM);
        k_gemm_nn<<<g, 256, 0, stream>>>(query, attW, qp, BB, DD, QQ);
    }
    k_gzero<<<1, 256, 0, stream>>>(gcnt);
    k_gcount<<<NB_SCAN, 256, 0, stream>>>(batch, gcnt);
    k_gscan<<<1, 256, 0, stream>>>(gcnt, goffs);
    k_scores<<<wave_blocks, 256, 0, stream>>>(P, GS, qp, batch, sarr);
    k_pool<<<BB, 256, 0, stream>>>(P, GS, sarr, goffs, gcnt, pr);
    {
        dim3 g((CC + BN - 1) / BN, (BB + BM - 1) / BM);
        k_gemm_nt<<<g, 256, 0, stream>>>(pr, lin_w, out, BB, CC, DD, lin_b);
    }
}

// Round 5
// 1017.722 us; speedup vs baseline: 1.7655x; 1.0863x over previous
//
#include <hip/hip_runtime.h>
#include <hip/hip_bf16.h>
#include <math.h>

#define N_NODES 50000
#define N_EDGES 250000
#define BB      128
#define DD      302
#define QQ      600
#define CC      2000
#define NEG_SLOPE 0.2f
#define GS      304        // padded row stride for G and P (16B-aligned rows)
#define KP      320        // padded K (10 x 32)
#define SA      40         // LDS k-stride in shorts (32 + 8 pad)
#define KSTEPS  10         // KP / 32

typedef __attribute__((ext_vector_type(8))) short short8;
typedef __attribute__((ext_vector_type(4))) float f32x4;

// ---------------------------------------------------------------- CSR build
__global__ void k_deg_init(int* deg, int* cursor) {
    int i = blockIdx.x * blockDim.x + threadIdx.x;
    if (i < N_NODES) { deg[i] = 1; cursor[i] = 0; }  // 1 = self loop
}

__global__ void k_histogram(const int* __restrict__ dst, int* deg) {
    int e = blockIdx.x * blockDim.x + threadIdx.x;
    if (e < N_EDGES) atomicAdd(&deg[dst[e]], 1);
}

__global__ void k_scan_block(const int* __restrict__ deg, int* offs, int* partials) {
    __shared__ int sh[256];
    int i = blockIdx.x * 256 + threadIdx.x;
    int v = (i < N_NODES) ? deg[i] : 0;
    sh[threadIdx.x] = v;
    __syncthreads();
    for (int d = 1; d < 256; d <<= 1) {
        int t = (threadIdx.x >= d) ? sh[threadIdx.x - d] : 0;
        __syncthreads();
        sh[threadIdx.x] += t;
        __syncthreads();
    }
    if (i < N_NODES) offs[i] = sh[threadIdx.x] - v;   // exclusive
    if (threadIdx.x == 255) partials[blockIdx.x] = sh[255];
}

__global__ void k_scan_partials(int* partials, int nb) {
    __shared__ int sh[256];
    int v = (threadIdx.x < nb) ? partials[threadIdx.x] : 0;
    sh[threadIdx.x] = v;
    __syncthreads();
    for (int d = 1; d < 256; d <<= 1) {
        int t = (threadIdx.x >= d) ? sh[threadIdx.x - d] : 0;
        __syncthreads();
        sh[threadIdx.x] += t;
        __syncthreads();
    }
    if (threadIdx.x < nb) partials[threadIdx.x] = sh[threadIdx.x] - v;  // exclusive
}

__global__ void k_scan_add(int* offs, const int* __restrict__ partials) {
    int i = blockIdx.x * 256 + threadIdx.x;
    if (i < N_NODES) offs[i] += partials[blockIdx.x];
}

__global__ void k_scatter(const int* __restrict__ src, const int* __restrict__ dst,
                          const int* __restrict__ offs, int* cursor, int* esrc) {
    int i = blockIdx.x * blockDim.x + threadIdx.x;
    if (i < N_EDGES) {
        int d = dst[i];
        int pos = offs[d] + atomicAdd(&cursor[d], 1);
        esrc[pos] = src[i];
    } else if (i < N_EDGES + N_NODES) {
        int n = i - N_EDGES;
        int pos = offs[n] + atomicAdd(&cursor[n], 1);
        esrc[pos] = n;   // self loop
    }
}

// ---------------------------------------------------------------- theta -> padded hi/lo bf16
__global__ void k_theta_prep(const float* __restrict__ theta,
                             unsigned short* __restrict__ thhi,
                             unsigned short* __restrict__ thlo) {
    int idx = blockIdx.x * 256 + threadIdx.x;
    if (idx >= KP * KP) return;
    int n = idx / KP, k = idx % KP;
    float v = (n < DD && k < DD) ? theta[n * DD + k] : 0.f;
    unsigned int u  = __float_as_uint(v);
    unsigned int uh = (u + 0x8000u) & 0xffff0000u;    // round-half-up bf16
    float hf = __uint_as_float(uh);
    float lo = v - hf;
    unsigned int ul = (__float_as_uint(lo) + 0x8000u) >> 16;
    thhi[idx] = (unsigned short)(uh >> 16);
    thlo[idx] = (unsigned short)ul;
}

// v_s = theta^T @ att_src, v_d = theta^T @ att_dst; appended as B rows DD, DD+1.
__global__ void k_attvec(const float* __restrict__ theta,
                         const float* __restrict__ att_src,
                         const float* __restrict__ att_dst,
                         unsigned short* __restrict__ thhi,
                         unsigned short* __restrict__ thlo) {
    int k = blockIdx.x * 256 + threadIdx.x;
    if (k >= DD) return;
    float vs = 0.f, vd = 0.f;
    for (int j = 0; j < DD; j++) {
        float t = theta[j * DD + k];      // coalesced over k
        vs += t * att_src[j];
        vd += t * att_dst[j];
    }
    unsigned int u, uh, ul;
    u  = __float_as_uint(vs);
    uh = (u + 0x8000u) & 0xffff0000u;
    ul = (__float_as_uint(vs - __uint_as_float(uh)) + 0x8000u) >> 16;
    thhi[(size_t)DD * KP + k] = (unsigned short)(uh >> 16);
    thlo[(size_t)DD * KP + k] = (unsigned short)ul;
    u  = __float_as_uint(vd);
    uh = (u + 0x8000u) & 0xffff0000u;
    ul = (__float_as_uint(vd - __uint_as_float(uh)) + 0x8000u) >> 16;
    thhi[(size_t)(DD + 1) * KP + k] = (unsigned short)(uh >> 16);
    thlo[(size_t)(DD + 1) * KP + k] = (unsigned short)ul;
}

// ---------------------------------------------------------------- split-bf16 MFMA GEMM
// C[m,n] = sum_k A[m,k] * theta[n,k]; A fp32 [M x lda], C fp32 [M x GS].
// Cols DD / DD+1 of the extended B hold v_s / v_d -> routed to a_s / a_d.
__global__ __launch_bounds__(256) void k_mfma_gemm(const float* __restrict__ A, int lda,
                                                   const unsigned short* __restrict__ Bhg,
                                                   const unsigned short* __restrict__ Blg,
                                                   float* __restrict__ C,
                                                   float* __restrict__ a_s,
                                                   float* __restrict__ a_d, int M) {
    __shared__ short Ah[2][64 * SA];
    __shared__ short Al[2][64 * SA];

    const int tid   = threadIdx.x;
    const int m0    = blockIdx.x * 64;
    const int lane  = tid & 63;
    const int wave  = tid >> 6;         // 0..3
    const int q     = lane >> 4;        // 0..3
    const int mr    = lane & 15;
    const int nbase = wave * 80;

    f32x4 acc[4][5];
    #pragma unroll
    for (int i = 0; i < 4; i++)
        #pragma unroll
        for (int j = 0; j < 5; j++)
            acc[i][j] = (f32x4){0.f, 0.f, 0.f, 0.f};

    const int  srow  = tid >> 2;        // 0..63
    const int  schk  = tid & 3;         // 0..3
    const bool rowok = (m0 + srow) < M;
    const float* arow = A + (size_t)(m0 + srow) * lda;

    float fst[8];
    auto load_stage = [&](int k0) {
        if (lda == GS) {
            float4 v0 = {0.f,0.f,0.f,0.f}, v1 = {0.f,0.f,0.f,0.f};
            if (rowok) {
                v0 = *(const float4*)(arow + k0 + schk * 8);
                v1 = *(const float4*)(arow + k0 + schk * 8 + 4);
            }
            fst[0]=v0.x; fst[1]=v0.y; fst[2]=v0.z; fst[3]=v0.w;
            fst[4]=v1.x; fst[5]=v1.y; fst[6]=v1.z; fst[7]=v1.w;
        } else {
            #pragma unroll
            for (int p = 0; p < 4; p++) {
                int k = k0 + schk * 8 + p * 2;
                float2 t = {0.f, 0.f};
                if (rowok && k < DD) t = *(const float2*)(arow + k);  // DD even
                fst[p*2] = t.x; fst[p*2+1] = t.y;
            }
        }
    };
    auto write_stage = [&](int buf) {
        unsigned int hp[4], lp[4];
        #pragma unroll
        for (int p = 0; p < 4; p++) {
            float a = fst[p*2], b = fst[p*2+1];
            __hip_bfloat162 h2 = __float22bfloat162_rn(make_float2(a, b));
            unsigned int hu; __builtin_memcpy(&hu, &h2, 4);
            float ha = __uint_as_float(hu << 16);
            float hb = __uint_as_float(hu & 0xffff0000u);
            __hip_bfloat162 l2 = __float22bfloat162_rn(make_float2(a - ha, b - hb));
            unsigned int lu; __builtin_memcpy(&lu, &l2, 4);
            hp[p] = hu; lp[p] = lu;
        }
        uint4 H = {hp[0], hp[1], hp[2], hp[3]};
        uint4 L = {lp[0], lp[1], lp[2], lp[3]};
        *(uint4*)&Ah[buf][srow * SA + schk * 8] = H;
        *(uint4*)&Al[buf][srow * SA + schk * 8] = L;
    };

    load_stage(0);
    write_stage(0);
    __syncthreads();

    for (int ks = 0; ks < KSTEPS; ks++) {
        const int cur = ks & 1;
        const int k0  = ks * 32;
        if (ks + 1 < KSTEPS) load_stage(k0 + 32);     // issue early; consumed after MFMA

        short8 bh[5], bl[5];
        #pragma unroll
        for (int nt = 0; nt < 5; nt++) {
            size_t boff = (size_t)(nbase + nt * 16 + mr) * KP + k0 + q * 8;
            bh[nt] = *(const short8*)(Bhg + boff);
            bl[nt] = *(const short8*)(Blg + boff);
        }
        short8 ah[4], al[4];
        #pragma unroll
        for (int mt = 0; mt < 4; mt++) {
            ah[mt] = *(const short8*)&Ah[cur][(mt * 16 + mr) * SA + q * 8];
            al[mt] = *(const short8*)&Al[cur][(mt * 16 + mr) * SA + q * 8];
        }
        #pragma unroll
        for (int mt = 0; mt < 4; mt++)
            #pragma unroll
            for (int nt = 0; nt < 5; nt++) {
                acc[mt][nt] = __builtin_amdgcn_mfma_f32_16x16x32_bf16(ah[mt], bh[nt], acc[mt][nt], 0, 0, 0);
                acc[mt][nt] = __builtin_amdgcn_mfma_f32_16x16x32_bf16(ah[mt], bl[nt], acc[mt][nt], 0, 0, 0);
                acc[mt][nt] = __builtin_amdgcn_mfma_f32_16x16x32_bf16(al[mt], bh[nt], acc[mt][nt], 0, 0, 0);
            }

        if (ks + 1 < KSTEPS) write_stage(cur ^ 1);    // other buffer: safe pre-barrier
        __syncthreads();
    }

    // epilogue: C/D layout col=lane&15, row=(lane>>4)*4+reg
    #pragma unroll
    for (int mt = 0; mt < 4; mt++) {
        int row_b = m0 + mt * 16 + q * 4;
        #pragma unroll
        for (int nt = 0; nt < 5; nt++) {
            int col = nbase + nt * 16 + mr;
            if (col > DD + 1) continue;
            #pragma unroll
            for (int r = 0; r < 4; r++) {
                int row = row_b + r;
                if (row >= M) continue;
                float v = acc[mt][nt][r];
                if (col < DD)            C[(size_t)row * GS + col] = v;
                else if (col == DD)      a_s[row] = v;
                else                     a_d[row] = v;
            }
        }
    }
}

// ---------------------------------------------------------------- tiled SGEMM (final linear)
#define BM 64
#define BN 64
#define BK 16
__global__ __launch_bounds__(256) void k_gemm_nt(const float* __restrict__ A,
                                                 const float* __restrict__ B,
                                                 float* __restrict__ C,
                                                 int M, int N, int K,
                                                 const float* __restrict__ bias) {
    __shared__ float As[BK][BM + 4];
    __shared__ float Bs[BK][BN + 4];
    int m0 = blockIdx.y * BM;
    int n0 = blockIdx.x * BN;
    int tid = threadIdx.x;
    int tr = tid >> 4;
    int tc = tid & 15;
    float acc[4][4] = {};
    for (int k0 = 0; k0 < K; k0 += BK) {
        #pragma unroll
        for (int j = 0; j < 4; j++) {
            int e = tid + 256 * j;
            int r = e >> 4;
            int k = e & 15;
            int gk = k0 + k;
            int gm = m0 + r;
            float va = 0.f;
            if (gm < M && gk < K) va = A[(size_t)gm * K + gk];
            As[k][r] = va;
            int gn = n0 + r;
            float vb = 0.f;
            if (gn < N && gk < K) vb = B[(size_t)gn * K + gk];
            Bs[k][r] = vb;
        }
        __syncthreads();
        #pragma unroll
        for (int k = 0; k < BK; k++) {
            float a[4], b[4];
            #pragma unroll
            for (int i = 0; i < 4; i++) a[i] = As[k][tr * 4 + i];
            #pragma unroll
            for (int j = 0; j < 4; j++) b[j] = Bs[k][tc * 4 + j];
            #pragma unroll
            for (int i = 0; i < 4; i++)
                #pragma unroll
                for (int j = 0; j < 4; j++)
                    acc[i][j] += a[i] * b[j];
        }
        __syncthreads();
    }
    #pragma unroll
    for (int i = 0; i < 4; i++) {
        int gm = m0 + tr * 4 + i;
        if (gm >= M) continue;
        #pragma unroll
        for (int j = 0; j < 4; j++) {
            int gn = n0 + tc * 4 + j;
            if (gn < N) {
                float v = acc[i][j];
                if (bias) v += bias[gn];
                C[(size_t)gm * N + gn] = v;
            }
        }
    }
}

// ---------------------------------------------------------------- qp = query @ attW  (thread/output)
__global__ __launch_bounds__(256) void k_qp(const float* __restrict__ query,
                                            const float* __restrict__ attW,
                                            float* __restrict__ qp) {
    int b = blockIdx.y;
    int d = blockIdx.x * 256 + threadIdx.x;
    if (d >= DD) return;
    const float* qrow = query + (size_t)b * QQ;
    float acc = 0.f;
    #pragma unroll 8
    for (int q = 0; q < QQ; q++) acc += qrow[q] * attW[(size_t)q * DD + d];
    qp[(size_t)b * DD + d] = acc;
}

// ---------------------------------------------------------------- softmax-aggregate (wave / dst node)
__global__ __launch_bounds__(256) void k_aggregate(const float* __restrict__ h, int ld,
                                                   const float* __restrict__ a_s,
                                                   const float* __restrict__ a_d,
                                                   const int* __restrict__ offs,
                                                   const int* __restrict__ deg,
                                                   const int* __restrict__ esrc,
                                                   const float* __restrict__ bias,
                                                   float* __restrict__ out) {
    int gid = blockIdx.x * blockDim.x + threadIdx.x;
    int n = gid >> 6, lane = gid & 63;
    if (n >= N_NODES) return;
    int beg = offs[n], cnt = deg[n];
    float adn = a_d[n];
    float m = -INFINITY;
    for (int i = lane; i < cnt; i += 64) {
        float e = a_s[esrc[beg + i]] + adn;
        e = (e > 0.f) ? e : NEG_SLOPE * e;
        m = fmaxf(m, e);
    }
    for (int off = 32; off; off >>= 1) m = fmaxf(m, __shfl_xor(m, off));
    float den = 0.f;
    for (int i = lane; i < cnt; i += 64) {
        float e = a_s[esrc[beg + i]] + adn;
        e = (e > 0.f) ? e : NEG_SLOPE * e;
        den += __expf(e - m);
    }
    for (int off = 32; off; off >>= 1) den += __shfl_xor(den, off);
    float inv_den = 1.f / den;
    float acc[5] = {0.f, 0.f, 0.f, 0.f, 0.f};
    for (int i = 0; i < cnt; i++) {
        int s = esrc[beg + i];
        float e = a_s[s] + adn;
        e = (e > 0.f) ? e : NEG_SLOPE * e;
        float w = __expf(e - m) * inv_den;
        const float* row = h + (size_t)s * ld;
        #pragma unroll
        for (int j = 0; j < 5; j++) {
            int f = lane + 64 * j;
            if (f < DD) acc[j] += w * row[f];
        }
    }
    #pragma unroll
    for (int j = 0; j < 5; j++) {
        int f = lane + 64 * j;
        if (f < DD) {
            float v = acc[j] + bias[f];
            out[(size_t)n * ld + f] = fmaxf(v, 0.f);
        }
    }
    if (lane < GS - DD) out[(size_t)n * ld + DD + lane] = 0.f;  // zero pad cols
}

// ---------------------------------------------------------------- pooling pieces
__global__ void k_gzero(int* gcnt) {
    if (threadIdx.x < BB) gcnt[threadIdx.x] = 0;
}

__global__ void k_gcount(const int* __restrict__ batch, int* gcnt) {
    int i = blockIdx.x * blockDim.x + threadIdx.x;
    if (i < N_NODES) atomicAdd(&gcnt[batch[i]], 1);
}

__global__ void k_gscan(const int* __restrict__ gcnt, int* goffs) {
    __shared__ int sh[BB];
    int t = threadIdx.x;
    if (t < BB) sh[t] = gcnt[t];
    __syncthreads();
    if (t == 0) {
        int run = 0;
        for (int i = 0; i < BB; i++) { int v = sh[i]; sh[i] = run; run += v; }
    }
    __syncthreads();
    if (t < BB) goffs[t] = sh[t];
}

__global__ void k_scores(const float* __restrict__ h, int ld,
                         const float* __restrict__ qp,
                         const int* __restrict__ batch, float* sarr) {
    int gid = blockIdx.x * blockDim.x + threadIdx.x;
    int n = gid >> 6, lane = gid & 63;
    if (n >= N_NODES) return;
    const float* row = h + (size_t)n * ld;
    const float* q = qp + (size_t)batch[n] * DD;
    float acc = 0.f;
    for (int j = lane; j < DD; j += 64) acc += row[j] * q[j];
    for (int off = 32; off; off >>= 1) acc += __shfl_down(acc, off);
    if (lane == 0) sarr[n] = acc * 0.04082482904638630f;   // 1/sqrt(600)
}

__global__ __launch_bounds__(256) void k_pool(const float* __restrict__ h, int ld,
                                              const float* __restrict__ sarr,
                                              const int* __restrict__ goffs,
                                              const int* __restrict__ gcnt,
                                              float* __restrict__ pooledrelu) {
    int b = blockIdx.x;
    int beg = goffs[b], cnt = gcnt[b];
    __shared__ float red[256];
    float m = -INFINITY;
    for (int i = threadIdx.x; i < cnt; i += 256) m = fmaxf(m, sarr[beg + i]);
    red[threadIdx.x] = m;
    __syncthreads();
    for (int d = 128; d; d >>= 1) {
        if (threadIdx.x < d) red[threadIdx.x] = fmaxf(red[threadIdx.x], red[threadIdx.x + d]);
        __syncthreads();
    }
    m = red[0];
    __syncthreads();
    float den = 0.f;
    for (int i = threadIdx.x; i < cnt; i += 256) den += __expf(sarr[beg + i] - m);
    red[threadIdx.x] = den;
    __syncthreads();
    for (int d = 128; d; d >>= 1) {
        if (threadIdx.x < d) red[threadIdx.x] += red[threadIdx.x + d];
        __syncthreads();
    }
    den = red[0];
    float inv = (cnt > 0) ? 1.f / den : 0.f;
    float acc0 = 0.f, acc1 = 0.f;
    int f0 = threadIdx.x, f1 = threadIdx.x + 256;
    for (int i = 0; i < cnt; i++) {
        float w = __expf(sarr[beg + i] - m) * inv;
        const float* row = h + (size_t)(beg + i) * ld;
        if (f0 < DD) acc0 += w * row[f0];
        if (f1 < DD) acc1 += w * row[f1];
    }
    if (f0 < DD) pooledrelu[(size_t)b * DD + f0] = fmaxf(acc0, 0.f);
    if (f1 < DD) pooledrelu[(size_t)b * DD + f1] = fmaxf(acc1, 0.f);
}

// ---------------------------------------------------------------- launch
extern "C" void kernel_launch(void* const* d_in, const int* in_sizes, int n_in,
                              void* d_out, int out_size, void* d_ws, size_t ws_size,
                              hipStream_t stream) {
    const float* x        = (const float*)d_in[0];
    const int*   edges    = (const int*)d_in[1];   // [2, E]
    const float* query    = (const float*)d_in[2];
    const int*   batch    = (const int*)d_in[3];
    const float* theta    = (const float*)d_in[4];
    const float* att_src  = (const float*)d_in[5];
    const float* att_dst  = (const float*)d_in[6];
    const float* gat_bias = (const float*)d_in[7];
    const float* attW     = (const float*)d_in[8];
    const float* lin_w    = (const float*)d_in[9];
    const float* lin_b    = (const float*)d_in[10];
    float* out = (float*)d_out;

    char* ws = (char*)d_ws;
    size_t off = 0;
    auto alloc = [&](size_t bytes) -> void* {
        off = (off + 255) & ~(size_t)255;
        void* p = ws + off;
        off += bytes;
        return p;
    };

    float* G    = (float*)alloc((size_t)N_NODES * GS * 4);   // gemm output (padded stride)
    float* P    = (float*)alloc((size_t)N_NODES * GS * 4);   // layer output (padded stride)
    unsigned short* thhi = (unsigned short*)alloc((size_t)KP * KP * 2);
    unsigned short* thlo = (unsigned short*)alloc((size_t)KP * KP * 2);
    float* a_s  = (float*)alloc((size_t)N_NODES * 4);
    float* a_d  = (float*)alloc((size_t)N_NODES * 4);
    float* sarr = (float*)alloc((size_t)N_NODES * 4);
    int* deg    = (int*)alloc((size_t)N_NODES * 4);
    int* cursor = (int*)alloc((size_t)N_NODES * 4);
    int* offs   = (int*)alloc((size_t)N_NODES * 4);
    int* esrc   = (int*)alloc((size_t)(N_EDGES + N_NODES) * 4);
    int* partials = (int*)alloc(256 * 4);
    int* gcnt   = (int*)alloc(BB * 4);
    int* goffs  = (int*)alloc(BB * 4);
    float* qp   = (float*)alloc((size_t)BB * DD * 4);
    float* pr   = (float*)alloc((size_t)BB * DD * 4);

    const int* e_src = edges;
    const int* e_dst = edges + N_EDGES;

    const int NB_SCAN = (N_NODES + 255) / 256;   // 196

    // ---- CSR build
    k_deg_init<<<NB_SCAN, 256, 0, stream>>>(deg, cursor);
    k_histogram<<<(N_EDGES + 255) / 256, 256, 0, stream>>>(e_dst, deg);
    k_scan_block<<<NB_SCAN, 256, 0, stream>>>(deg, offs, partials);
    k_scan_partials<<<1, 256, 0, stream>>>(partials, NB_SCAN);
    k_scan_add<<<NB_SCAN, 256, 0, stream>>>(offs, partials);
    k_scatter<<<(N_EDGES + N_NODES + 255) / 256, 256, 0, stream>>>(e_src, e_dst, offs, cursor, esrc);

    // ---- theta hi/lo split + attention-vector rows (once; shared across layers)
    k_theta_prep<<<(KP * KP + 255) / 256, 256, 0, stream>>>(theta, thhi, thlo);
    k_attvec<<<(DD + 255) / 256, 256, 0, stream>>>(theta, att_src, att_dst, thhi, thlo);

    // ---- 3 GAT layers
    int mfma_blocks = (N_NODES + 63) / 64;   // 782
    int wave_blocks = (N_NODES + 3) / 4;
    const float* cur = x;
    int cur_ld = DD;
    for (int layer = 0; layer < 3; layer++) {
        k_mfma_gemm<<<mfma_blocks, 256, 0, stream>>>(cur, cur_ld, thhi, thlo, G, a_s, a_d, N_NODES);
        k_aggregate<<<wave_blocks, 256, 0, stream>>>(G, GS, a_s, a_d, offs, deg, esrc, gat_bias, P);
        cur = P;
        cur_ld = GS;
    }

    // ---- attention pooling + classifier
    {
        dim3 g((DD + 255) / 256, BB);
        k_qp<<<g, 256, 0, stream>>>(query, attW, qp);
    }
    k_gzero<<<1, 256, 0, stream>>>(gcnt);
    k_gcount<<<NB_SCAN, 256, 0, stream>>>(batch, gcnt);
    k_gscan<<<1, 256, 0, stream>>>(gcnt, goffs);
    k_scores<<<wave_blocks, 256, 0, stream>>>(P, GS, qp, batch, sarr);
    k_pool<<<BB, 256, 0, stream>>>(P, GS, sarr, goffs, gcnt, pr);
    {
        dim3 g((CC + BN - 1) / BN, (BB + BM - 1) / BM);
        k_gemm_nt<<<g, 256, 0, stream>>>(pr, lin_w, out, BB, CC, DD, lin_b);
    }
}

// Round 6
// 940.777 us; speedup vs baseline: 1.9099x; 1.0818x over previous
//
#include <hip/hip_runtime.h>
#include <hip/hip_bf16.h>
#include <math.h>

#define N_NODES 50000
#define N_EDGES 250000
#define BB      128
#define DD      302
#define QQ      600
#define CC      2000
#define NEG_SLOPE 0.2f
#define GS      304        // padded row stride for G and P (16B-aligned rows)
#define KP      320        // padded K (10 x 32)
#define SA      40         // LDS k-stride in shorts (32 + 8 pad)
#define KSTEPS  10         // KP / 32
#define PC      64         // nodes per pooling chunk

typedef __attribute__((ext_vector_type(8))) short short8;
typedef __attribute__((ext_vector_type(4))) float f32x4;

// ---------------------------------------------------------------- CSR build
__global__ void k_deg_init(int* deg, int* cursor) {
    int i = blockIdx.x * blockDim.x + threadIdx.x;
    if (i < N_NODES) { deg[i] = 1; cursor[i] = 0; }  // 1 = self loop
}

__global__ void k_histogram(const int* __restrict__ dst, int* deg) {
    int e = blockIdx.x * blockDim.x + threadIdx.x;
    if (e < N_EDGES) atomicAdd(&deg[dst[e]], 1);
}

__global__ void k_scan_block(const int* __restrict__ deg, int* offs, int* partials) {
    __shared__ int sh[256];
    int i = blockIdx.x * 256 + threadIdx.x;
    int v = (i < N_NODES) ? deg[i] : 0;
    sh[threadIdx.x] = v;
    __syncthreads();
    for (int d = 1; d < 256; d <<= 1) {
        int t = (threadIdx.x >= d) ? sh[threadIdx.x - d] : 0;
        __syncthreads();
        sh[threadIdx.x] += t;
        __syncthreads();
    }
    if (i < N_NODES) offs[i] = sh[threadIdx.x] - v;   // exclusive
    if (threadIdx.x == 255) partials[blockIdx.x] = sh[255];
}

__global__ void k_scan_partials(int* partials, int nb) {
    __shared__ int sh[256];
    int v = (threadIdx.x < nb) ? partials[threadIdx.x] : 0;
    sh[threadIdx.x] = v;
    __syncthreads();
    for (int d = 1; d < 256; d <<= 1) {
        int t = (threadIdx.x >= d) ? sh[threadIdx.x - d] : 0;
        __syncthreads();
        sh[threadIdx.x] += t;
        __syncthreads();
    }
    if (threadIdx.x < nb) partials[threadIdx.x] = sh[threadIdx.x] - v;  // exclusive
}

__global__ void k_scan_add(int* offs, const int* __restrict__ partials) {
    int i = blockIdx.x * 256 + threadIdx.x;
    if (i < N_NODES) offs[i] += partials[blockIdx.x];
}

__global__ void k_scatter(const int* __restrict__ src, const int* __restrict__ dst,
                          const int* __restrict__ offs, int* cursor, int* esrc) {
    int i = blockIdx.x * blockDim.x + threadIdx.x;
    if (i < N_EDGES) {
        int d = dst[i];
        int pos = offs[d] + atomicAdd(&cursor[d], 1);
        esrc[pos] = src[i];
    } else if (i < N_EDGES + N_NODES) {
        int n = i - N_EDGES;
        int pos = offs[n] + atomicAdd(&cursor[n], 1);
        esrc[pos] = n;   // self loop
    }
}

// ---------------------------------------------------------------- theta -> padded hi/lo bf16
__global__ void k_theta_prep(const float* __restrict__ theta,
                             unsigned short* __restrict__ thhi,
                             unsigned short* __restrict__ thlo) {
    int idx = blockIdx.x * 256 + threadIdx.x;
    if (idx >= KP * KP) return;
    int n = idx / KP, k = idx % KP;
    float v = (n < DD && k < DD) ? theta[n * DD + k] : 0.f;
    unsigned int u  = __float_as_uint(v);
    unsigned int uh = (u + 0x8000u) & 0xffff0000u;    // round-half-up bf16
    float hf = __uint_as_float(uh);
    float lo = v - hf;
    unsigned int ul = (__float_as_uint(lo) + 0x8000u) >> 16;
    thhi[idx] = (unsigned short)(uh >> 16);
    thlo[idx] = (unsigned short)ul;
}

// v_s = theta^T @ att_src, v_d = theta^T @ att_dst; appended as B rows DD, DD+1.
__global__ void k_attvec(const float* __restrict__ theta,
                         const float* __restrict__ att_src,
                         const float* __restrict__ att_dst,
                         unsigned short* __restrict__ thhi,
                         unsigned short* __restrict__ thlo) {
    int k = blockIdx.x * 256 + threadIdx.x;
    if (k >= DD) return;
    float vs = 0.f, vd = 0.f;
    for (int j = 0; j < DD; j++) {
        float t = theta[j * DD + k];      // coalesced over k
        vs += t * att_src[j];
        vd += t * att_dst[j];
    }
    unsigned int u, uh, ul;
    u  = __float_as_uint(vs);
    uh = (u + 0x8000u) & 0xffff0000u;
    ul = (__float_as_uint(vs - __uint_as_float(uh)) + 0x8000u) >> 16;
    thhi[(size_t)DD * KP + k] = (unsigned short)(uh >> 16);
    thlo[(size_t)DD * KP + k] = (unsigned short)ul;
    u  = __float_as_uint(vd);
    uh = (u + 0x8000u) & 0xffff0000u;
    ul = (__float_as_uint(vd - __uint_as_float(uh)) + 0x8000u) >> 16;
    thhi[(size_t)(DD + 1) * KP + k] = (unsigned short)(uh >> 16);
    thlo[(size_t)(DD + 1) * KP + k] = (unsigned short)ul;
}

// ---------------------------------------------------------------- split-bf16 MFMA GEMM
__global__ __launch_bounds__(256) void k_mfma_gemm(const float* __restrict__ A, int lda,
                                                   const unsigned short* __restrict__ Bhg,
                                                   const unsigned short* __restrict__ Blg,
                                                   float* __restrict__ C,
                                                   float* __restrict__ a_s,
                                                   float* __restrict__ a_d, int M) {
    __shared__ short Ah[2][64 * SA];
    __shared__ short Al[2][64 * SA];

    const int tid   = threadIdx.x;
    const int m0    = blockIdx.x * 64;
    const int lane  = tid & 63;
    const int wave  = tid >> 6;         // 0..3
    const int q     = lane >> 4;        // 0..3
    const int mr    = lane & 15;
    const int nbase = wave * 80;

    f32x4 acc[4][5];
    #pragma unroll
    for (int i = 0; i < 4; i++)
        #pragma unroll
        for (int j = 0; j < 5; j++)
            acc[i][j] = (f32x4){0.f, 0.f, 0.f, 0.f};

    const int  srow  = tid >> 2;        // 0..63
    const int  schk  = tid & 3;         // 0..3
    const bool rowok = (m0 + srow) < M;
    const float* arow = A + (size_t)(m0 + srow) * lda;

    float fst[8];
    auto load_stage = [&](int k0) {
        if (lda == GS) {
            float4 v0 = {0.f,0.f,0.f,0.f}, v1 = {0.f,0.f,0.f,0.f};
            if (rowok) {
                v0 = *(const float4*)(arow + k0 + schk * 8);
                v1 = *(const float4*)(arow + k0 + schk * 8 + 4);
            }
            fst[0]=v0.x; fst[1]=v0.y; fst[2]=v0.z; fst[3]=v0.w;
            fst[4]=v1.x; fst[5]=v1.y; fst[6]=v1.z; fst[7]=v1.w;
        } else {
            #pragma unroll
            for (int p = 0; p < 4; p++) {
                int k = k0 + schk * 8 + p * 2;
                float2 t = {0.f, 0.f};
                if (rowok && k < DD) t = *(const float2*)(arow + k);  // DD even
                fst[p*2] = t.x; fst[p*2+1] = t.y;
            }
        }
    };
    auto write_stage = [&](int buf) {
        unsigned int hp[4], lp[4];
        #pragma unroll
        for (int p = 0; p < 4; p++) {
            float a = fst[p*2], b = fst[p*2+1];
            __hip_bfloat162 h2 = __float22bfloat162_rn(make_float2(a, b));
            unsigned int hu; __builtin_memcpy(&hu, &h2, 4);
            float ha = __uint_as_float(hu << 16);
            float hb = __uint_as_float(hu & 0xffff0000u);
            __hip_bfloat162 l2 = __float22bfloat162_rn(make_float2(a - ha, b - hb));
            unsigned int lu; __builtin_memcpy(&lu, &l2, 4);
            hp[p] = hu; lp[p] = lu;
        }
        uint4 H = {hp[0], hp[1], hp[2], hp[3]};
        uint4 L = {lp[0], lp[1], lp[2], lp[3]};
        *(uint4*)&Ah[buf][srow * SA + schk * 8] = H;
        *(uint4*)&Al[buf][srow * SA + schk * 8] = L;
    };

    load_stage(0);
    write_stage(0);
    __syncthreads();

    for (int ks = 0; ks < KSTEPS; ks++) {
        const int cur = ks & 1;
        const int k0  = ks * 32;
        if (ks + 1 < KSTEPS) load_stage(k0 + 32);     // issue early; consumed after MFMA

        short8 bh[5], bl[5];
        #pragma unroll
        for (int nt = 0; nt < 5; nt++) {
            size_t boff = (size_t)(nbase + nt * 16 + mr) * KP + k0 + q * 8;
            bh[nt] = *(const short8*)(Bhg + boff);
            bl[nt] = *(const short8*)(Blg + boff);
        }
        short8 ah[4], al[4];
        #pragma unroll
        for (int mt = 0; mt < 4; mt++) {
            ah[mt] = *(const short8*)&Ah[cur][(mt * 16 + mr) * SA + q * 8];
            al[mt] = *(const short8*)&Al[cur][(mt * 16 + mr) * SA + q * 8];
        }
        #pragma unroll
        for (int mt = 0; mt < 4; mt++)
            #pragma unroll
            for (int nt = 0; nt < 5; nt++) {
                acc[mt][nt] = __builtin_amdgcn_mfma_f32_16x16x32_bf16(ah[mt], bh[nt], acc[mt][nt], 0, 0, 0);
                acc[mt][nt] = __builtin_amdgcn_mfma_f32_16x16x32_bf16(ah[mt], bl[nt], acc[mt][nt], 0, 0, 0);
                acc[mt][nt] = __builtin_amdgcn_mfma_f32_16x16x32_bf16(al[mt], bh[nt], acc[mt][nt], 0, 0, 0);
            }

        if (ks + 1 < KSTEPS) write_stage(cur ^ 1);    // other buffer: safe pre-barrier
        __syncthreads();
    }

    // epilogue: C/D layout col=lane&15, row=(lane>>4)*4+reg
    #pragma unroll
    for (int mt = 0; mt < 4; mt++) {
        int row_b = m0 + mt * 16 + q * 4;
        #pragma unroll
        for (int nt = 0; nt < 5; nt++) {
            int col = nbase + nt * 16 + mr;
            if (col > DD + 1) continue;
            #pragma unroll
            for (int r = 0; r < 4; r++) {
                int row = row_b + r;
                if (row >= M) continue;
                float v = acc[mt][nt][r];
                if (col < DD)            C[(size_t)row * GS + col] = v;
                else if (col == DD)      a_s[row] = v;
                else                     a_d[row] = v;
            }
        }
    }
}

// ---------------------------------------------------------------- tiled SGEMM (final linear)
#define BM 64
#define BN 64
#define BK 16
__global__ __launch_bounds__(256) void k_gemm_nt(const float* __restrict__ A,
                                                 const float* __restrict__ B,
                                                 float* __restrict__ C,
                                                 int M, int N, int K,
                                                 const float* __restrict__ bias) {
    __shared__ float As[BK][BM + 4];
    __shared__ float Bs[BK][BN + 4];
    int m0 = blockIdx.y * BM;
    int n0 = blockIdx.x * BN;
    int tid = threadIdx.x;
    int tr = tid >> 4;
    int tc = tid & 15;
    float acc[4][4] = {};
    for (int k0 = 0; k0 < K; k0 += BK) {
        #pragma unroll
        for (int j = 0; j < 4; j++) {
            int e = tid + 256 * j;
            int r = e >> 4;
            int k = e & 15;
            int gk = k0 + k;
            int gm = m0 + r;
            float va = 0.f;
            if (gm < M && gk < K) va = A[(size_t)gm * K + gk];
            As[k][r] = va;
            int gn = n0 + r;
            float vb = 0.f;
            if (gn < N && gk < K) vb = B[(size_t)gn * K + gk];
            Bs[k][r] = vb;
        }
        __syncthreads();
        #pragma unroll
        for (int k = 0; k < BK; k++) {
            float a[4], b[4];
            #pragma unroll
            for (int i = 0; i < 4; i++) a[i] = As[k][tr * 4 + i];
            #pragma unroll
            for (int j = 0; j < 4; j++) b[j] = Bs[k][tc * 4 + j];
            #pragma unroll
            for (int i = 0; i < 4; i++)
                #pragma unroll
                for (int j = 0; j < 4; j++)
                    acc[i][j] += a[i] * b[j];
        }
        __syncthreads();
    }
    #pragma unroll
    for (int i = 0; i < 4; i++) {
        int gm = m0 + tr * 4 + i;
        if (gm >= M) continue;
        #pragma unroll
        for (int j = 0; j < 4; j++) {
            int gn = n0 + tc * 4 + j;
            if (gn < N) {
                float v = acc[i][j];
                if (bias) v += bias[gn];
                C[(size_t)gm * N + gn] = v;
            }
        }
    }
}

// ---------------------------------------------------------------- qp = query @ attW  (thread/output)
__global__ __launch_bounds__(256) void k_qp(const float* __restrict__ query,
                                            const float* __restrict__ attW,
                                            float* __restrict__ qp) {
    int b = blockIdx.y;
    int d = blockIdx.x * 256 + threadIdx.x;
    if (d >= DD) return;
    const float* qrow = query + (size_t)b * QQ;
    float acc = 0.f;
    #pragma unroll 8
    for (int q = 0; q < QQ; q++) acc += qrow[q] * attW[(size_t)q * DD + d];
    qp[(size_t)b * DD + d] = acc;
}

// ---------------------------------------------------------------- softmax-aggregate (wave / dst node)
__global__ __launch_bounds__(256) void k_aggregate(const float* __restrict__ h, int ld,
                                                   const float* __restrict__ a_s,
                                                   const float* __restrict__ a_d,
                                                   const int* __restrict__ offs,
                                                   const int* __restrict__ deg,
                                                   const int* __restrict__ esrc,
                                                   const float* __restrict__ bias,
                                                   float* __restrict__ out) {
    int gid = blockIdx.x * blockDim.x + threadIdx.x;
    int n = gid >> 6, lane = gid & 63;
    if (n >= N_NODES) return;
    int beg = offs[n], cnt = deg[n];
    float adn = a_d[n];
    float m = -INFINITY;
    for (int i = lane; i < cnt; i += 64) {
        float e = a_s[esrc[beg + i]] + adn;
        e = (e > 0.f) ? e : NEG_SLOPE * e;
        m = fmaxf(m, e);
    }
    for (int off = 32; off; off >>= 1) m = fmaxf(m, __shfl_xor(m, off));
    float den = 0.f;
    for (int i = lane; i < cnt; i += 64) {
        float e = a_s[esrc[beg + i]] + adn;
        e = (e > 0.f) ? e : NEG_SLOPE * e;
        den += __expf(e - m);
    }
    for (int off = 32; off; off >>= 1) den += __shfl_xor(den, off);
    float inv_den = 1.f / den;
    float acc[5] = {0.f, 0.f, 0.f, 0.f, 0.f};
    for (int i = 0; i < cnt; i++) {
        int s = esrc[beg + i];
        float e = a_s[s] + adn;
        e = (e > 0.f) ? e : NEG_SLOPE * e;
        float w = __expf(e - m) * inv_den;
        const float* row = h + (size_t)s * ld;
        #pragma unroll
        for (int j = 0; j < 5; j++) {
            int f = lane + 64 * j;
            if (f < DD) acc[j] += w * row[f];
        }
    }
    #pragma unroll
    for (int j = 0; j < 5; j++) {
        int f = lane + 64 * j;
        if (f < DD) {
            float v = acc[j] + bias[f];
            out[(size_t)n * ld + f] = fmaxf(v, 0.f);
        }
    }
    if (lane < GS - DD) out[(size_t)n * ld + DD + lane] = 0.f;  // zero pad cols
}

// ---------------------------------------------------------------- pooling pieces
__global__ void k_gzero(int* gcnt) {
    if (threadIdx.x < BB) gcnt[threadIdx.x] = 0;
}

__global__ void k_gcount(const int* __restrict__ batch, int* gcnt) {
    int i = blockIdx.x * blockDim.x + threadIdx.x;
    if (i < N_NODES) atomicAdd(&gcnt[batch[i]], 1);
}

__global__ void k_gscan(const int* __restrict__ gcnt, int* goffs) {
    __shared__ int sh[BB];
    int t = threadIdx.x;
    if (t < BB) sh[t] = gcnt[t];
    __syncthreads();
    if (t == 0) {
        int run = 0;
        for (int i = 0; i < BB; i++) { int v = sh[i]; sh[i] = run; run += v; }
    }
    __syncthreads();
    if (t < BB) goffs[t] = sh[t];
}

__global__ void k_scores(const float* __restrict__ h, int ld,
                         const float* __restrict__ qp,
                         const int* __restrict__ batch, float* sarr) {
    int gid = blockIdx.x * blockDim.x + threadIdx.x;
    int n = gid >> 6, lane = gid & 63;
    if (n >= N_NODES) return;
    const float* row = h + (size_t)n * ld;
    const float* q = qp + (size_t)batch[n] * DD;
    float acc = 0.f;
    for (int j = lane; j < DD; j += 64) acc += row[j] * q[j];
    for (int off = 32; off; off >>= 1) acc += __shfl_down(acc, off);
    if (lane == 0) sarr[n] = acc * 0.04082482904638630f;   // 1/sqrt(600)
}

// per-graph softmax stats over sarr
__global__ __launch_bounds__(256) void k_gstats(const float* __restrict__ sarr,
                                                const int* __restrict__ goffs,
                                                const int* __restrict__ gcnt,
                                                float* __restrict__ gm,
                                                float* __restrict__ gdeninv) {
    int b = blockIdx.x;
    int beg = goffs[b], cnt = gcnt[b];
    __shared__ float red[256];
    float m = -INFINITY;
    for (int i = threadIdx.x; i < cnt; i += 256) m = fmaxf(m, sarr[beg + i]);
    red[threadIdx.x] = m;
    __syncthreads();
    for (int d = 128; d; d >>= 1) {
        if (threadIdx.x < d) red[threadIdx.x] = fmaxf(red[threadIdx.x], red[threadIdx.x + d]);
        __syncthreads();
    }
    m = red[0];
    __syncthreads();
    float den = 0.f;
    for (int i = threadIdx.x; i < cnt; i += 256) den += __expf(sarr[beg + i] - m);
    red[threadIdx.x] = den;
    __syncthreads();
    for (int d = 128; d; d >>= 1) {
        if (threadIdx.x < d) red[threadIdx.x] += red[threadIdx.x + d];
        __syncthreads();
    }
    if (threadIdx.x == 0) {
        gm[b] = m;
        gdeninv[b] = (cnt > 0) ? 1.f / red[0] : 0.f;
    }
}

__global__ void k_wn(const float* __restrict__ sarr, const int* __restrict__ batch,
                     const float* __restrict__ gm, const float* __restrict__ gdeninv,
                     float* __restrict__ wn) {
    int n = blockIdx.x * 256 + threadIdx.x;
    if (n >= N_NODES) return;
    int b = batch[n];
    wn[n] = __expf(sarr[n] - gm[b]) * gdeninv[b];
}

__global__ void k_pzero(float* pooled) {
    int i = blockIdx.x * 256 + threadIdx.x;
    if (i < BB * DD) pooled[i] = 0.f;
}

// node-chunk-parallel weighted segment sum (batch sorted; flush at graph boundaries)
__global__ __launch_bounds__(256) void k_poolacc(const float* __restrict__ h, int ld,
                                                 const float* __restrict__ wn,
                                                 const int* __restrict__ batch,
                                                 float* __restrict__ pooled) {
    int c0 = blockIdx.x * PC;
    if (c0 >= N_NODES) return;
    int nmax = N_NODES - c0; if (nmax > PC) nmax = PC;
    __shared__ int   sb[PC];
    __shared__ float sw[PC];
    for (int i = threadIdx.x; i < nmax; i += 256) {
        sb[i] = batch[c0 + i];
        sw[i] = wn[c0 + i];
    }
    __syncthreads();
    int f0 = threadIdx.x, f1 = threadIdx.x + 256;
    float a0 = 0.f, a1 = 0.f;
    int g = sb[0];
    for (int i = 0; i < nmax; i++) {
        int bi = sb[i];
        if (bi != g) {                       // wave-uniform branch
            if (f0 < DD) atomicAdd(&pooled[(size_t)g * DD + f0], a0);
            if (f1 < DD) atomicAdd(&pooled[(size_t)g * DD + f1], a1);
            a0 = 0.f; a1 = 0.f; g = bi;
        }
        float w = sw[i];
        const float* row = h + (size_t)(c0 + i) * ld;
        if (f0 < DD) a0 += w * row[f0];
        if (f1 < DD) a1 += w * row[f1];
    }
    if (f0 < DD) atomicAdd(&pooled[(size_t)g * DD + f0], a0);
    if (f1 < DD) atomicAdd(&pooled[(size_t)g * DD + f1], a1);
}

__global__ void k_prelu(const float* __restrict__ pooled, float* __restrict__ pr) {
    int i = blockIdx.x * 256 + threadIdx.x;
    if (i < BB * DD) pr[i] = fmaxf(pooled[i], 0.f);
}

// ---------------------------------------------------------------- launch
extern "C" void kernel_launch(void* const* d_in, const int* in_sizes, int n_in,
                              void* d_out, int out_size, void* d_ws, size_t ws_size,
                              hipStream_t stream) {
    const float* x        = (const float*)d_in[0];
    const int*   edges    = (const int*)d_in[1];   // [2, E]
    const float* query    = (const float*)d_in[2];
    const int*   batch    = (const int*)d_in[3];
    const float* theta    = (const float*)d_in[4];
    const float* att_src  = (const float*)d_in[5];
    const float* att_dst  = (const float*)d_in[6];
    const float* gat_bias = (const float*)d_in[7];
    const float* attW     = (const float*)d_in[8];
    const float* lin_w    = (const float*)d_in[9];
    const float* lin_b    = (const float*)d_in[10];
    float* out = (float*)d_out;

    char* ws = (char*)d_ws;
    size_t off = 0;
    auto alloc = [&](size_t bytes) -> void* {
        off = (off + 255) & ~(size_t)255;
        void* p = ws + off;
        off += bytes;
        return p;
    };

    float* G    = (float*)alloc((size_t)N_NODES * GS * 4);   // gemm output (padded stride)
    float* P    = (float*)alloc((size_t)N_NODES * GS * 4);   // layer output (padded stride)
    unsigned short* thhi = (unsigned short*)alloc((size_t)KP * KP * 2);
    unsigned short* thlo = (unsigned short*)alloc((size_t)KP * KP * 2);
    float* a_s  = (float*)alloc((size_t)N_NODES * 4);
    float* a_d  = (float*)alloc((size_t)N_NODES * 4);
    float* sarr = (float*)alloc((size_t)N_NODES * 4);
    float* wn   = (float*)alloc((size_t)N_NODES * 4);
    int* deg    = (int*)alloc((size_t)N_NODES * 4);
    int* cursor = (int*)alloc((size_t)N_NODES * 4);
    int* offs   = (int*)alloc((size_t)N_NODES * 4);
    int* esrc   = (int*)alloc((size_t)(N_EDGES + N_NODES) * 4);
    int* partials = (int*)alloc(256 * 4);
    int* gcnt   = (int*)alloc(BB * 4);
    int* goffs  = (int*)alloc(BB * 4);
    float* gm   = (float*)alloc(BB * 4);
    float* gdi  = (float*)alloc(BB * 4);
    float* qp   = (float*)alloc((size_t)BB * DD * 4);
    float* pooled = (float*)alloc((size_t)BB * DD * 4);
    float* pr   = (float*)alloc((size_t)BB * DD * 4);

    const int* e_src = edges;
    const int* e_dst = edges + N_EDGES;

    const int NB_SCAN = (N_NODES + 255) / 256;   // 196

    // ---- CSR build
    k_deg_init<<<NB_SCAN, 256, 0, stream>>>(deg, cursor);
    k_histogram<<<(N_EDGES + 255) / 256, 256, 0, stream>>>(e_dst, deg);
    k_scan_block<<<NB_SCAN, 256, 0, stream>>>(deg, offs, partials);
    k_scan_partials<<<1, 256, 0, stream>>>(partials, NB_SCAN);
    k_scan_add<<<NB_SCAN, 256, 0, stream>>>(offs, partials);
    k_scatter<<<(N_EDGES + N_NODES + 255) / 256, 256, 0, stream>>>(e_src, e_dst, offs, cursor, esrc);

    // ---- theta hi/lo split + attention-vector rows (once; shared across layers)
    k_theta_prep<<<(KP * KP + 255) / 256, 256, 0, stream>>>(theta, thhi, thlo);
    k_attvec<<<(DD + 255) / 256, 256, 0, stream>>>(theta, att_src, att_dst, thhi, thlo);

    // ---- 3 GAT layers
    int mfma_blocks = (N_NODES + 63) / 64;   // 782
    int wave_blocks = (N_NODES + 3) / 4;
    const float* cur = x;
    int cur_ld = DD;
    for (int layer = 0; layer < 3; layer++) {
        k_mfma_gemm<<<mfma_blocks, 256, 0, stream>>>(cur, cur_ld, thhi, thlo, G, a_s, a_d, N_NODES);
        k_aggregate<<<wave_blocks, 256, 0, stream>>>(G, GS, a_s, a_d, offs, deg, esrc, gat_bias, P);
        cur = P;
        cur_ld = GS;
    }

    // ---- attention pooling + classifier
    {
        dim3 g((DD + 255) / 256, BB);
        k_qp<<<g, 256, 0, stream>>>(query, attW, qp);
    }
    k_gzero<<<1, 256, 0, stream>>>(gcnt);
    k_gcount<<<NB_SCAN, 256, 0, stream>>>(batch, gcnt);
    k_gscan<<<1, 256, 0, stream>>>(gcnt, goffs);
    k_scores<<<wave_blocks, 256, 0, stream>>>(P, GS, qp, batch, sarr);
    k_gstats<<<BB, 256, 0, stream>>>(sarr, goffs, gcnt, gm, gdi);
    k_wn<<<NB_SCAN, 256, 0, stream>>>(sarr, batch, gm, gdi, wn);
    k_pzero<<<(BB * DD + 255) / 256, 256, 0, stream>>>(pooled);
    k_poolacc<<<(N_NODES + PC - 1) / PC, 256, 0, stream>>>(P, GS, wn, batch, pooled);
    k_prelu<<<(BB * DD + 255) / 256, 256, 0, stream>>>(pooled, pr);
    {
        dim3 g((CC + BN - 1) / BN, (BB + BM - 1) / BM);
        k_gemm_nt<<<g, 256, 0, stream>>>(pr, lin_w, out, BB, CC, DD, lin_b);
    }
}

// Round 7
// 819.142 us; speedup vs baseline: 2.1935x; 1.1485x over previous
//
#include <hip/hip_runtime.h>
#include <hip/hip_bf16.h>
#include <math.h>

#define N_NODES 50000
#define N_EDGES 250000
#define BB      128
#define DD      302
#define QQ      600
#define CC      2000
#define NEG_SLOPE 0.2f
#define GS      304        // padded row stride for G and P (16B-aligned rows)
#define KP      320        // padded K (10 x 32)
#define SA      40         // LDS k-stride in shorts (32 + 8 pad)
#define KSTEPS  10         // KP / 32
#define PC      64         // nodes per pooling chunk

typedef __attribute__((ext_vector_type(8))) short short8;
typedef __attribute__((ext_vector_type(4))) float f32x4;

// ---------------------------------------------------------------- CSR build
__global__ void k_deg_init(int* deg, int* cursor) {
    int i = blockIdx.x * blockDim.x + threadIdx.x;
    if (i < N_NODES) { deg[i] = 1; cursor[i] = 0; }  // 1 = self loop
}

__global__ void k_histogram(const int* __restrict__ dst, int* deg) {
    int e = blockIdx.x * blockDim.x + threadIdx.x;
    if (e < N_EDGES) atomicAdd(&deg[dst[e]], 1);
}

__global__ void k_scan_block(const int* __restrict__ deg, int* offs, int* partials) {
    __shared__ int sh[256];
    int i = blockIdx.x * 256 + threadIdx.x;
    int v = (i < N_NODES) ? deg[i] : 0;
    sh[threadIdx.x] = v;
    __syncthreads();
    for (int d = 1; d < 256; d <<= 1) {
        int t = (threadIdx.x >= d) ? sh[threadIdx.x - d] : 0;
        __syncthreads();
        sh[threadIdx.x] += t;
        __syncthreads();
    }
    if (i < N_NODES) offs[i] = sh[threadIdx.x] - v;   // exclusive
    if (threadIdx.x == 255) partials[blockIdx.x] = sh[255];
}

__global__ void k_scan_partials(int* partials, int nb) {
    __shared__ int sh[256];
    int v = (threadIdx.x < nb) ? partials[threadIdx.x] : 0;
    sh[threadIdx.x] = v;
    __syncthreads();
    for (int d = 1; d < 256; d <<= 1) {
        int t = (threadIdx.x >= d) ? sh[threadIdx.x - d] : 0;
        __syncthreads();
        sh[threadIdx.x] += t;
        __syncthreads();
    }
    if (threadIdx.x < nb) partials[threadIdx.x] = sh[threadIdx.x] - v;  // exclusive
}

__global__ void k_scan_add(int* offs, const int* __restrict__ partials) {
    int i = blockIdx.x * 256 + threadIdx.x;
    if (i < N_NODES) offs[i] += partials[blockIdx.x];
}

__global__ void k_scatter(const int* __restrict__ src, const int* __restrict__ dst,
                          const int* __restrict__ offs, int* cursor, int* esrc) {
    int i = blockIdx.x * blockDim.x + threadIdx.x;
    if (i < N_EDGES) {
        int d = dst[i];
        int pos = offs[d] + atomicAdd(&cursor[d], 1);
        esrc[pos] = src[i];
    } else if (i < N_EDGES + N_NODES) {
        int n = i - N_EDGES;
        int pos = offs[n] + atomicAdd(&cursor[n], 1);
        esrc[pos] = n;   // self loop
    }
}

// ---------------------------------------------------------------- theta -> padded hi/lo bf16
__global__ void k_theta_prep(const float* __restrict__ theta,
                             unsigned short* __restrict__ thhi,
                             unsigned short* __restrict__ thlo) {
    int idx = blockIdx.x * 256 + threadIdx.x;
    if (idx >= KP * KP) return;
    int n = idx / KP, k = idx % KP;
    float v = (n < DD && k < DD) ? theta[n * DD + k] : 0.f;
    unsigned int u  = __float_as_uint(v);
    unsigned int uh = (u + 0x8000u) & 0xffff0000u;    // round-half-up bf16
    float hf = __uint_as_float(uh);
    float lo = v - hf;
    unsigned int ul = (__float_as_uint(lo) + 0x8000u) >> 16;
    thhi[idx] = (unsigned short)(uh >> 16);
    thlo[idx] = (unsigned short)ul;
}

// v_s = theta^T @ att_src, v_d = theta^T @ att_dst; appended as B rows DD, DD+1.
__global__ void k_attvec(const float* __restrict__ theta,
                         const float* __restrict__ att_src,
                         const float* __restrict__ att_dst,
                         unsigned short* __restrict__ thhi,
                         unsigned short* __restrict__ thlo) {
    int k = blockIdx.x * 256 + threadIdx.x;
    if (k >= DD) return;
    float vs = 0.f, vd = 0.f;
    for (int j = 0; j < DD; j++) {
        float t = theta[j * DD + k];      // coalesced over k
        vs += t * att_src[j];
        vd += t * att_dst[j];
    }
    unsigned int u, uh, ul;
    u  = __float_as_uint(vs);
    uh = (u + 0x8000u) & 0xffff0000u;
    ul = (__float_as_uint(vs - __uint_as_float(uh)) + 0x8000u) >> 16;
    thhi[(size_t)DD * KP + k] = (unsigned short)(uh >> 16);
    thlo[(size_t)DD * KP + k] = (unsigned short)ul;
    u  = __float_as_uint(vd);
    uh = (u + 0x8000u) & 0xffff0000u;
    ul = (__float_as_uint(vd - __uint_as_float(uh)) + 0x8000u) >> 16;
    thhi[(size_t)(DD + 1) * KP + k] = (unsigned short)(uh >> 16);
    thlo[(size_t)(DD + 1) * KP + k] = (unsigned short)ul;
}

// ---------------------------------------------------------------- split-bf16 MFMA GEMM
__global__ __launch_bounds__(256) void k_mfma_gemm(const float* __restrict__ A, int lda,
                                                   const unsigned short* __restrict__ Bhg,
                                                   const unsigned short* __restrict__ Blg,
                                                   float* __restrict__ C,
                                                   float* __restrict__ a_s,
                                                   float* __restrict__ a_d, int M) {
    __shared__ short Ah[2][64 * SA];
    __shared__ short Al[2][64 * SA];

    const int tid   = threadIdx.x;
    const int m0    = blockIdx.x * 64;
    const int lane  = tid & 63;
    const int wave  = tid >> 6;         // 0..3
    const int q     = lane >> 4;        // 0..3
    const int mr    = lane & 15;
    const int nbase = wave * 80;

    f32x4 acc[4][5];
    #pragma unroll
    for (int i = 0; i < 4; i++)
        #pragma unroll
        for (int j = 0; j < 5; j++)
            acc[i][j] = (f32x4){0.f, 0.f, 0.f, 0.f};

    const int  srow  = tid >> 2;        // 0..63
    const int  schk  = tid & 3;         // 0..3
    const bool rowok = (m0 + srow) < M;
    const float* arow = A + (size_t)(m0 + srow) * lda;

    float fst[8];
    auto load_stage = [&](int k0) {
        if (lda == GS) {
            float4 v0 = {0.f,0.f,0.f,0.f}, v1 = {0.f,0.f,0.f,0.f};
            if (rowok) {
                v0 = *(const float4*)(arow + k0 + schk * 8);
                v1 = *(const float4*)(arow + k0 + schk * 8 + 4);
            }
            fst[0]=v0.x; fst[1]=v0.y; fst[2]=v0.z; fst[3]=v0.w;
            fst[4]=v1.x; fst[5]=v1.y; fst[6]=v1.z; fst[7]=v1.w;
        } else {
            #pragma unroll
            for (int p = 0; p < 4; p++) {
                int k = k0 + schk * 8 + p * 2;
                float2 t = {0.f, 0.f};
                if (rowok && k < DD) t = *(const float2*)(arow + k);  // DD even
                fst[p*2] = t.x; fst[p*2+1] = t.y;
            }
        }
    };
    auto write_stage = [&](int buf) {
        unsigned int hp[4], lp[4];
        #pragma unroll
        for (int p = 0; p < 4; p++) {
            float a = fst[p*2], b = fst[p*2+1];
            __hip_bfloat162 h2 = __float22bfloat162_rn(make_float2(a, b));
            unsigned int hu; __builtin_memcpy(&hu, &h2, 4);
            float ha = __uint_as_float(hu << 16);
            float hb = __uint_as_float(hu & 0xffff0000u);
            __hip_bfloat162 l2 = __float22bfloat162_rn(make_float2(a - ha, b - hb));
            unsigned int lu; __builtin_memcpy(&lu, &l2, 4);
            hp[p] = hu; lp[p] = lu;
        }
        uint4 H = {hp[0], hp[1], hp[2], hp[3]};
        uint4 L = {lp[0], lp[1], lp[2], lp[3]};
        *(uint4*)&Ah[buf][srow * SA + schk * 8] = H;
        *(uint4*)&Al[buf][srow * SA + schk * 8] = L;
    };

    load_stage(0);
    write_stage(0);
    __syncthreads();

    for (int ks = 0; ks < KSTEPS; ks++) {
        const int cur = ks & 1;
        const int k0  = ks * 32;
        if (ks + 1 < KSTEPS) load_stage(k0 + 32);     // issue early; consumed after MFMA

        short8 bh[5], bl[5];
        #pragma unroll
        for (int nt = 0; nt < 5; nt++) {
            size_t boff = (size_t)(nbase + nt * 16 + mr) * KP + k0 + q * 8;
            bh[nt] = *(const short8*)(Bhg + boff);
            bl[nt] = *(const short8*)(Blg + boff);
        }
        short8 ah[4], al[4];
        #pragma unroll
        for (int mt = 0; mt < 4; mt++) {
            ah[mt] = *(const short8*)&Ah[cur][(mt * 16 + mr) * SA + q * 8];
            al[mt] = *(const short8*)&Al[cur][(mt * 16 + mr) * SA + q * 8];
        }
        #pragma unroll
        for (int mt = 0; mt < 4; mt++)
            #pragma unroll
            for (int nt = 0; nt < 5; nt++) {
                acc[mt][nt] = __builtin_amdgcn_mfma_f32_16x16x32_bf16(ah[mt], bh[nt], acc[mt][nt], 0, 0, 0);
                acc[mt][nt] = __builtin_amdgcn_mfma_f32_16x16x32_bf16(ah[mt], bl[nt], acc[mt][nt], 0, 0, 0);
                acc[mt][nt] = __builtin_amdgcn_mfma_f32_16x16x32_bf16(al[mt], bh[nt], acc[mt][nt], 0, 0, 0);
            }

        if (ks + 1 < KSTEPS) write_stage(cur ^ 1);    // other buffer: safe pre-barrier
        __syncthreads();
    }

    // epilogue: C/D layout col=lane&15, row=(lane>>4)*4+reg
    #pragma unroll
    for (int mt = 0; mt < 4; mt++) {
        int row_b = m0 + mt * 16 + q * 4;
        #pragma unroll
        for (int nt = 0; nt < 5; nt++) {
            int col = nbase + nt * 16 + mr;
            if (col > DD + 1) continue;
            #pragma unroll
            for (int r = 0; r < 4; r++) {
                int row = row_b + r;
                if (row >= M) continue;
                float v = acc[mt][nt][r];
                if (col < DD)            C[(size_t)row * GS + col] = v;
                else if (col == DD)      a_s[row] = v;
                else                     a_d[row] = v;
            }
        }
    }
}

// ---------------------------------------------------------------- tiled SGEMM (final linear)
#define BM 64
#define BN 64
#define BK 16
__global__ __launch_bounds__(256) void k_gemm_nt(const float* __restrict__ A,
                                                 const float* __restrict__ B,
                                                 float* __restrict__ C,
                                                 int M, int N, int K,
                                                 const float* __restrict__ bias) {
    __shared__ float As[BK][BM + 4];
    __shared__ float Bs[BK][BN + 4];
    int m0 = blockIdx.y * BM;
    int n0 = blockIdx.x * BN;
    int tid = threadIdx.x;
    int tr = tid >> 4;
    int tc = tid & 15;
    float acc[4][4] = {};
    for (int k0 = 0; k0 < K; k0 += BK) {
        #pragma unroll
        for (int j = 0; j < 4; j++) {
            int e = tid + 256 * j;
            int r = e >> 4;
            int k = e & 15;
            int gk = k0 + k;
            int gm = m0 + r;
            float va = 0.f;
            if (gm < M && gk < K) va = A[(size_t)gm * K + gk];
            As[k][r] = va;
            int gn = n0 + r;
            float vb = 0.f;
            if (gn < N && gk < K) vb = B[(size_t)gn * K + gk];
            Bs[k][r] = vb;
        }
        __syncthreads();
        #pragma unroll
        for (int k = 0; k < BK; k++) {
            float a[4], b[4];
            #pragma unroll
            for (int i = 0; i < 4; i++) a[i] = As[k][tr * 4 + i];
            #pragma unroll
            for (int j = 0; j < 4; j++) b[j] = Bs[k][tc * 4 + j];
            #pragma unroll
            for (int i = 0; i < 4; i++)
                #pragma unroll
                for (int j = 0; j < 4; j++)
                    acc[i][j] += a[i] * b[j];
        }
        __syncthreads();
    }
    #pragma unroll
    for (int i = 0; i < 4; i++) {
        int gm = m0 + tr * 4 + i;
        if (gm >= M) continue;
        #pragma unroll
        for (int j = 0; j < 4; j++) {
            int gn = n0 + tc * 4 + j;
            if (gn < N) {
                float v = acc[i][j];
                if (bias) v += bias[gn];
                C[(size_t)gm * N + gn] = v;
            }
        }
    }
}

// ---------------------------------------------------------------- qp = query @ attW  (thread/output)
__global__ __launch_bounds__(256) void k_qp(const float* __restrict__ query,
                                            const float* __restrict__ attW,
                                            float* __restrict__ qp) {
    int b = blockIdx.y;
    int d = blockIdx.x * 256 + threadIdx.x;
    if (d >= DD) return;
    const float* qrow = query + (size_t)b * QQ;
    float acc = 0.f;
    #pragma unroll 8
    for (int q = 0; q < QQ; q++) acc += qrow[q] * attW[(size_t)q * DD + d];
    qp[(size_t)b * DD + d] = acc;
}

// ---------------------------------------------------------------- softmax-aggregate (wave / dst node)
__global__ __launch_bounds__(256) void k_aggregate(const float* __restrict__ h, int ld,
                                                   const float* __restrict__ a_s,
                                                   const float* __restrict__ a_d,
                                                   const int* __restrict__ offs,
                                                   const int* __restrict__ deg,
                                                   const int* __restrict__ esrc,
                                                   const float* __restrict__ bias,
                                                   float* __restrict__ out) {
    int gid = blockIdx.x * blockDim.x + threadIdx.x;
    int n = gid >> 6, lane = gid & 63;
    if (n >= N_NODES) return;
    int beg = offs[n], cnt = deg[n];
    float adn = a_d[n];
    float m = -INFINITY;
    for (int i = lane; i < cnt; i += 64) {
        float e = a_s[esrc[beg + i]] + adn;
        e = (e > 0.f) ? e : NEG_SLOPE * e;
        m = fmaxf(m, e);
    }
    for (int off = 32; off; off >>= 1) m = fmaxf(m, __shfl_xor(m, off));
    float den = 0.f;
    for (int i = lane; i < cnt; i += 64) {
        float e = a_s[esrc[beg + i]] + adn;
        e = (e > 0.f) ? e : NEG_SLOPE * e;
        den += __expf(e - m);
    }
    for (int off = 32; off; off >>= 1) den += __shfl_xor(den, off);
    float inv_den = 1.f / den;
    float acc[5] = {0.f, 0.f, 0.f, 0.f, 0.f};
    for (int i = 0; i < cnt; i++) {
        int s = esrc[beg + i];
        float e = a_s[s] + adn;
        e = (e > 0.f) ? e : NEG_SLOPE * e;
        float w = __expf(e - m) * inv_den;
        const float* row = h + (size_t)s * ld;
        #pragma unroll
        for (int j = 0; j < 5; j++) {
            int f = lane + 64 * j;
            if (f < DD) acc[j] += w * row[f];
        }
    }
    #pragma unroll
    for (int j = 0; j < 5; j++) {
        int f = lane + 64 * j;
        if (f < DD) {
            float v = acc[j] + bias[f];
            out[(size_t)n * ld + f] = fmaxf(v, 0.f);
        }
    }
    if (lane < GS - DD) out[(size_t)n * ld + DD + lane] = 0.f;  // zero pad cols
}

// ---------------------------------------------------------------- pooling pieces
// batch is SORTED -> per-graph bounds via binary search (no atomics).
__global__ void k_gbounds(const int* __restrict__ batch, int* goffs, int* gcnt) {
    __shared__ int bound[BB + 1];
    int b = threadIdx.x;
    if (b <= BB) {
        int lo = 0, hi = N_NODES;
        while (lo < hi) {                 // first i with batch[i] >= b
            int mid = (lo + hi) >> 1;
            if (batch[mid] < b) lo = mid + 1; else hi = mid;
        }
        bound[b] = lo;
    }
    __syncthreads();
    if (b < BB) {
        goffs[b] = bound[b];
        gcnt[b]  = bound[b + 1] - bound[b];
    }
}

__global__ void k_scores(const float* __restrict__ h, int ld,
                         const float* __restrict__ qp,
                         const int* __restrict__ batch, float* sarr) {
    int gid = blockIdx.x * blockDim.x + threadIdx.x;
    int n = gid >> 6, lane = gid & 63;
    if (n >= N_NODES) return;
    const float* row = h + (size_t)n * ld;
    const float* q = qp + (size_t)batch[n] * DD;
    float acc = 0.f;
    for (int j = lane; j < DD; j += 64) acc += row[j] * q[j];
    for (int off = 32; off; off >>= 1) acc += __shfl_down(acc, off);
    if (lane == 0) sarr[n] = acc * 0.04082482904638630f;   // 1/sqrt(600)
}

// per-graph softmax stats over sarr
__global__ __launch_bounds__(256) void k_gstats(const float* __restrict__ sarr,
                                                const int* __restrict__ goffs,
                                                const int* __restrict__ gcnt,
                                                float* __restrict__ gm,
                                                float* __restrict__ gdeninv) {
    int b = blockIdx.x;
    int beg = goffs[b], cnt = gcnt[b];
    __shared__ float red[256];
    float m = -INFINITY;
    for (int i = threadIdx.x; i < cnt; i += 256) m = fmaxf(m, sarr[beg + i]);
    red[threadIdx.x] = m;
    __syncthreads();
    for (int d = 128; d; d >>= 1) {
        if (threadIdx.x < d) red[threadIdx.x] = fmaxf(red[threadIdx.x], red[threadIdx.x + d]);
        __syncthreads();
    }
    m = red[0];
    __syncthreads();
    float den = 0.f;
    for (int i = threadIdx.x; i < cnt; i += 256) den += __expf(sarr[beg + i] - m);
    red[threadIdx.x] = den;
    __syncthreads();
    for (int d = 128; d; d >>= 1) {
        if (threadIdx.x < d) red[threadIdx.x] += red[threadIdx.x + d];
        __syncthreads();
    }
    if (threadIdx.x == 0) {
        gm[b] = m;
        gdeninv[b] = (cnt > 0) ? 1.f / red[0] : 0.f;
    }
}

__global__ void k_wn(const float* __restrict__ sarr, const int* __restrict__ batch,
                     const float* __restrict__ gm, const float* __restrict__ gdeninv,
                     float* __restrict__ wn) {
    int n = blockIdx.x * 256 + threadIdx.x;
    if (n >= N_NODES) return;
    int b = batch[n];
    wn[n] = __expf(sarr[n] - gm[b]) * gdeninv[b];
}

__global__ void k_pzero(float* pooled) {
    int i = blockIdx.x * 256 + threadIdx.x;
    if (i < BB * DD) pooled[i] = 0.f;
}

// node-chunk-parallel weighted segment sum (batch sorted; flush at graph boundaries)
__global__ __launch_bounds__(256) void k_poolacc(const float* __restrict__ h, int ld,
                                                 const float* __restrict__ wn,
                                                 const int* __restrict__ batch,
                                                 float* __restrict__ pooled) {
    int c0 = blockIdx.x * PC;
    if (c0 >= N_NODES) return;
    int nmax = N_NODES - c0; if (nmax > PC) nmax = PC;
    __shared__ int   sb[PC];
    __shared__ float sw[PC];
    for (int i = threadIdx.x; i < nmax; i += 256) {
        sb[i] = batch[c0 + i];
        sw[i] = wn[c0 + i];
    }
    __syncthreads();
    int f0 = threadIdx.x, f1 = threadIdx.x + 256;
    float a0 = 0.f, a1 = 0.f;
    int g = sb[0];
    for (int i = 0; i < nmax; i++) {
        int bi = sb[i];
        if (bi != g) {                       // wave-uniform branch
            if (f0 < DD) atomicAdd(&pooled[(size_t)g * DD + f0], a0);
            if (f1 < DD) atomicAdd(&pooled[(size_t)g * DD + f1], a1);
            a0 = 0.f; a1 = 0.f; g = bi;
        }
        float w = sw[i];
        const float* row = h + (size_t)(c0 + i) * ld;
        if (f0 < DD) a0 += w * row[f0];
        if (f1 < DD) a1 += w * row[f1];
    }
    if (f0 < DD) atomicAdd(&pooled[(size_t)g * DD + f0], a0);
    if (f1 < DD) atomicAdd(&pooled[(size_t)g * DD + f1], a1);
}

__global__ void k_prelu(const float* __restrict__ pooled, float* __restrict__ pr) {
    int i = blockIdx.x * 256 + threadIdx.x;
    if (i < BB * DD) pr[i] = fmaxf(pooled[i], 0.f);
}

// ---------------------------------------------------------------- launch
extern "C" void kernel_launch(void* const* d_in, const int* in_sizes, int n_in,
                              void* d_out, int out_size, void* d_ws, size_t ws_size,
                              hipStream_t stream) {
    const float* x        = (const float*)d_in[0];
    const int*   edges    = (const int*)d_in[1];   // [2, E]
    const float* query    = (const float*)d_in[2];
    const int*   batch    = (const int*)d_in[3];
    const float* theta    = (const float*)d_in[4];
    const float* att_src  = (const float*)d_in[5];
    const float* att_dst  = (const float*)d_in[6];
    const float* gat_bias = (const float*)d_in[7];
    const float* attW     = (const float*)d_in[8];
    const float* lin_w    = (const float*)d_in[9];
    const float* lin_b    = (const float*)d_in[10];
    float* out = (float*)d_out;

    char* ws = (char*)d_ws;
    size_t off = 0;
    auto alloc = [&](size_t bytes) -> void* {
        off = (off + 255) & ~(size_t)255;
        void* p = ws + off;
        off += bytes;
        return p;
    };

    float* G    = (float*)alloc((size_t)N_NODES * GS * 4);   // gemm output (padded stride)
    float* P    = (float*)alloc((size_t)N_NODES * GS * 4);   // layer output (padded stride)
    unsigned short* thhi = (unsigned short*)alloc((size_t)KP * KP * 2);
    unsigned short* thlo = (unsigned short*)alloc((size_t)KP * KP * 2);
    float* a_s  = (float*)alloc((size_t)N_NODES * 4);
    float* a_d  = (float*)alloc((size_t)N_NODES * 4);
    float* sarr = (float*)alloc((size_t)N_NODES * 4);
    float* wn   = (float*)alloc((size_t)N_NODES * 4);
    int* deg    = (int*)alloc((size_t)N_NODES * 4);
    int* cursor = (int*)alloc((size_t)N_NODES * 4);
    int* offs   = (int*)alloc((size_t)N_NODES * 4);
    int* esrc   = (int*)alloc((size_t)(N_EDGES + N_NODES) * 4);
    int* partials = (int*)alloc(256 * 4);
    int* gcnt   = (int*)alloc(BB * 4);
    int* goffs  = (int*)alloc(BB * 4);
    float* gm   = (float*)alloc(BB * 4);
    float* gdi  = (float*)alloc(BB * 4);
    float* qp   = (float*)alloc((size_t)BB * DD * 4);
    float* pooled = (float*)alloc((size_t)BB * DD * 4);
    float* pr   = (float*)alloc((size_t)BB * DD * 4);

    const int* e_src = edges;
    const int* e_dst = edges + N_EDGES;

    const int NB_SCAN = (N_NODES + 255) / 256;   // 196

    // ---- CSR build
    k_deg_init<<<NB_SCAN, 256, 0, stream>>>(deg, cursor);
    k_histogram<<<(N_EDGES + 255) / 256, 256, 0, stream>>>(e_dst, deg);
    k_scan_block<<<NB_SCAN, 256, 0, stream>>>(deg, offs, partials);
    k_scan_partials<<<1, 256, 0, stream>>>(partials, NB_SCAN);
    k_scan_add<<<NB_SCAN, 256, 0, stream>>>(offs, partials);
    k_scatter<<<(N_EDGES + N_NODES + 255) / 256, 256, 0, stream>>>(e_src, e_dst, offs, cursor, esrc);

    // ---- theta hi/lo split + attention-vector rows (once; shared across layers)
    k_theta_prep<<<(KP * KP + 255) / 256, 256, 0, stream>>>(theta, thhi, thlo);
    k_attvec<<<(DD + 255) / 256, 256, 0, stream>>>(theta, att_src, att_dst, thhi, thlo);

    // ---- 3 GAT layers
    int mfma_blocks = (N_NODES + 63) / 64;   // 782
    int wave_blocks = (N_NODES + 3) / 4;
    const float* cur = x;
    int cur_ld = DD;
    for (int layer = 0; layer < 3; layer++) {
        k_mfma_gemm<<<mfma_blocks, 256, 0, stream>>>(cur, cur_ld, thhi, thlo, G, a_s, a_d, N_NODES);
        k_aggregate<<<wave_blocks, 256, 0, stream>>>(G, GS, a_s, a_d, offs, deg, esrc, gat_bias, P);
        cur = P;
        cur_ld = GS;
    }

    // ---- attention pooling + classifier
    {
        dim3 g((DD + 255) / 256, BB);
        k_qp<<<g, 256, 0, stream>>>(query, attW, qp);
    }
    k_gbounds<<<1, 256, 0, stream>>>(batch, goffs, gcnt);
    k_scores<<<wave_blocks, 256, 0, stream>>>(P, GS, qp, batch, sarr);
    k_gstats<<<BB, 256, 0, stream>>>(sarr, goffs, gcnt, gm, gdi);
    k_wn<<<NB_SCAN, 256, 0, stream>>>(sarr, batch, gm, gdi, wn);
    k_pzero<<<(BB * DD + 255) / 256, 256, 0, stream>>>(pooled);
    k_poolacc<<<(N_NODES + PC - 1) / PC, 256, 0, stream>>>(P, GS, wn, batch, pooled);
    k_prelu<<<(BB * DD + 255) / 256, 256, 0, stream>>>(pooled, pr);
    {
        dim3 g((CC + BN - 1) / BN, (BB + BM - 1) / BM);
        k_gemm_nt<<<g, 256, 0, stream>>>(pr, lin_w, out, BB, CC, DD, lin_b);
    }
}